// Round 7
// baseline (27625.403 us; speedup 1.0000x reference)
//
#include <hip/hip_runtime.h>

// Pointer network: encoder LSTM -> enc_proj -> decoder LSTM + attention argmax.
// B=512, S=100, D=2, H=256.
//
// TRAJECTORY = fp64-exact state evolution (R5 structure: h/c/gates/ep/dp all f64;
// produced the exact-score trajectory, absmax 30 = one tie-break miss).
// SELECTION  = np-faithful fp32 log_softmax (R6 fix, moved the 30): scores
// rounded to fp32 once; m=max; shifted=__fsub_rn(s,m); E=expf(shifted);
// sum(E) in NUMPY PAIRWISE ORDER for n=100 (8 accumulators over 0..95,
// combine ((r0+r1)+(r2+r3))+((r4+r5)+(r6+r7)), sequential tail 96..99);
// L=logf; lp=__fsub_rn(shifted,L) -- this quantization collapses sub-ulp(L)
// gaps into EXACT ties which argmax breaks to the LOWER index (jnp/np
// semantics). lp accumulated sequentially in fp32 (np axis-0 sum is
// sequential). Evidence: R1/R2/R3/R5 (raw-score argmax) all absmax=30;
// R6 (fp32-lp argmax, noisy fp32 states) absmax=25 -> tie-break verified,
// state noise was the remaining flip source. This round: exact states + that
// tie-break.
//
// 512 blocks x 256 threads, plain launch; co-residency for the group barrier
// via __launch_bounds__(256,2) + ~45KB LDS -> exactly 2 blocks/CU x 256 CUs.
// group g = bid&7, role r = bid>>3; group owns batch [g*64, g*64+64).

#define B_WENC 0ull
#define B_WDEC (B_WENC + 1024ull*256ull*8ull)
#define B_WE   (B_WDEC + 1024ull*256ull*8ull)
#define B_WD   (B_WE   + 256ull*256ull*8ull)
#define B_WXE  (B_WD   + 256ull*256ull*8ull)
#define B_WXD  (B_WXE  + 256ull*16ull*8ull)
#define B_H    (B_WXD  + 256ull*16ull*8ull)
#define B_XT   (B_H    + 2ull*256ull*512ull*8ull)
#define B_DIN  (B_XT   + 100ull*512ull*2ull*4ull)
#define B_DP   (B_DIN  + 512ull*2ull*4ull)
#define B_EP   (B_DP   + 512ull*256ull*8ull)
#define B_SYNC (B_EP   + 512ull*100ull*256ull*8ull)

__device__ __forceinline__ double sigmoid_d(double x) {
  return 1.0 / (1.0 + exp(-x));
}

__device__ __forceinline__ double shfl_xor_d(double v, int m) {
  const long long l = __double_as_longlong(v);
  int lo = (int)(l & 0xffffffffll), hi = (int)(l >> 32);
  lo = __shfl_xor(lo, m, 64);
  hi = __shfl_xor(hi, m, 64);
  return __longlong_as_double(((long long)hi << 32) | (unsigned int)lo);
}

__device__ __forceinline__ double wave64_sum_d(double v) {
  #pragma unroll
  for (int m = 1; m < 64; m <<= 1) v += shfl_xor_d(v, m);
  return v;
}

// flag/release barrier over the 64 blocks of one group (device-scope atomics).
__device__ __forceinline__ void group_barrier(int* flags, int* rel, int g, int r,
                                              int epoch) {
  __syncthreads();
  const int tid = threadIdx.x;
  if (tid < 64) {
    if (tid == 0)
      __hip_atomic_store(&flags[g*64 + r], epoch, __ATOMIC_RELEASE,
                         __HIP_MEMORY_SCOPE_AGENT);
    if (r == 0) {
      for (;;) {
        const int v = __hip_atomic_load(&flags[g*64 + tid], __ATOMIC_ACQUIRE,
                                        __HIP_MEMORY_SCOPE_AGENT);
        if (__all(v >= epoch)) break;
        __builtin_amdgcn_s_sleep(2);
      }
      if (tid == 0)
        __hip_atomic_store(&rel[g*32], epoch, __ATOMIC_RELEASE,
                           __HIP_MEMORY_SCOPE_AGENT);
    }
    if (tid == 0) {
      while (__hip_atomic_load(&rel[g*32], __ATOMIC_ACQUIRE,
                               __HIP_MEMORY_SCOPE_AGENT) < epoch)
        __builtin_amdgcn_s_sleep(2);
    }
  }
  __syncthreads();
}

struct SMem {
  double gred[4][4][64][4];  // [writer wave][unit][b][gate]  32 KB
  double ered[4][64][4];     // [writer wave][b][kk]           8 KB
  double sred[100][4];       // per-s per-wave f64 partials   3.2 KB
  float  scores[104];
  float  evals[104];
  float  red_m, red_L;
  float  bc_lp;
  int    bc_sel;
};

extern "C" __global__ void ptrnet_prep(
    const float* __restrict__ x,
    const float* __restrict__ eWih, const float* __restrict__ eWhh,
    const float* __restrict__ ebih, const float* __restrict__ ebhh,
    const float* __restrict__ dWih, const float* __restrict__ dWhh,
    const float* __restrict__ dbih, const float* __restrict__ dbhh,
    const float* __restrict__ We,  const float* __restrict__ Wd,
    const float* __restrict__ start, char* __restrict__ wsb)
{
  const int idx = blockIdx.x * blockDim.x + threadIdx.x;
  const int stride = gridDim.x * blockDim.x;
  double* WENC = (double*)(wsb + B_WENC);
  double* WDEC = (double*)(wsb + B_WDEC);
  double* WEd  = (double*)(wsb + B_WE);
  double* WDd  = (double*)(wsb + B_WD);
  double* WXE  = (double*)(wsb + B_WXE);
  double* WXD  = (double*)(wsb + B_WXD);
  double* Hd   = (double*)(wsb + B_H);
  float*  XT   = (float*)(wsb + B_XT);
  float*  DIN  = (float*)(wsb + B_DIN);
  int*    SY   = (int*)(wsb + B_SYNC);

  // Whh -> [r][u][uu][gate] in f64
  for (int i = idx; i < 1024*256; i += stride) {
    const int gate = i & 3, uu = (i >> 2) & 3, u = (i >> 4) & 255, rr = i >> 12;
    const int row = gate*256 + rr*4 + uu;
    WENC[i] = (double)eWhh[row*256 + u];
    WDEC[i] = (double)dWhh[row*256 + u];
  }
  // att_We / att_Wd -> [r][u][kk] in f64
  for (int i = idx; i < 256*256; i += stride) {
    const int kk = i & 3, u = (i >> 2) & 255, rr = i >> 10;
    const int row = rr*4 + kk;
    WEd[i] = (double)We[row*256 + u];
    WDd[i] = (double)Wd[row*256 + u];
  }
  // Wih + bias pack: [u][16] = {i0,i1,f0,f1,g0,g1,o0,o1, bi,bf,bg,bo, pad}
  for (int i = idx; i < 256*16; i += stride) {
    const int f = i & 15, u = i >> 4;
    double ve = 0.0, vd = 0.0;
    if (f < 8) {
      const int gg = f >> 1, d = f & 1;
      ve = (double)eWih[(gg*256+u)*2 + d];
      vd = (double)dWih[(gg*256+u)*2 + d];
    } else if (f < 12) {
      const int gg = f - 8;
      ve = (double)ebih[gg*256+u] + (double)ebhh[gg*256+u];
      vd = (double)dbih[gg*256+u] + (double)dbhh[gg*256+u];
    }
    WXE[i] = ve;
    WXD[i] = vd;
  }
  // x -> [t][b][d] (f32: exact values)
  for (int i = idx; i < 100*512*2; i += stride) {
    const int d = i & 1, b = (i >> 1) & 511, t = i >> 10;
    XT[i] = x[(b*100 + t)*2 + d];
  }
  for (int i = idx; i < 2*256*512; i += stride) Hd[i] = 0.0;
  for (int i = idx; i < 1024; i += stride) DIN[i] = start[i & 1];
  for (int i = idx; i < 1024; i += stride) SY[i] = 0;
}

extern "C" __global__ void __launch_bounds__(256, 2)
ptrnet_main(char* __restrict__ wsb,
            const float* __restrict__ att_be,
            const float* __restrict__ att_bd,
            const float* __restrict__ Vw,
            const float* __restrict__ Vb,
            float* __restrict__ out)
{
  __shared__ SMem sm;
  const int bid = blockIdx.x;
  const int g   = bid & 7;
  const int r   = bid >> 3;
  const int tid = threadIdx.x;
  const int lane = tid & 63;
  const int w = __builtin_amdgcn_readfirstlane(tid >> 6);
  const int bG = g * 64;
  const int myb = bG + r;

  double* hbuf = (double*)(wsb + B_H);
  float*  xT   = (float*)(wsb + B_XT);
  float*  din  = (float*)(wsb + B_DIN);
  double* dpw  = (double*)(wsb + B_DP);
  double* ep   = (double*)(wsb + B_EP);
  int* flags   = (int*)(wsb + B_SYNC);
  int* rel     = flags + 512;

  const double* Wg_e = (double*)(wsb + B_WENC) + r*(256*16);
  const double* Wg_d = (double*)(wsb + B_WDEC) + r*(256*16);
  const double* Weg  = (double*)(wsb + B_WE)   + r*(256*4);
  const double* Wdg  = (double*)(wsb + B_WD)   + r*(256*4);
  const double* WxbE = (double*)(wsb + B_WXE);
  const double* WxbD = (double*)(wsb + B_WXD);

  const double be_r = (double)att_be[4*r + (tid & 3)];
  const double bd_r = (double)att_bd[4*r + (tid & 3)];
  const double vb0  = (double)Vb[0];

  int epoch = 0;
  double c_state = 0.0;

  // ============================ encoder ============================
  for (int t = 0; t < 100; ++t) {
    const double* hsrc = hbuf + (t & 1) * 131072;
    double*       hdst = hbuf + ((t + 1) & 1) * 131072;
    double acc[4][4] = {};
    double epacc[4] = {0.0, 0.0, 0.0, 0.0};
    for (int jc = 0; jc < 4; ++jc) {
      const int u0 = w*64 + jc*16;
      double hreg[16];
      #pragma unroll
      for (int j = 0; j < 16; ++j) hreg[j] = hsrc[(u0+j)*512 + bG + lane];
      #pragma unroll
      for (int j = 0; j < 16; ++j) {
        const double hv = hreg[j];
        const double* wr = Wg_e + (u0+j)*16;
        #pragma unroll
        for (int q = 0; q < 4; ++q) {
          acc[q][0] = fma(wr[q*4+0], hv, acc[q][0]);
          acc[q][1] = fma(wr[q*4+1], hv, acc[q][1]);
          acc[q][2] = fma(wr[q*4+2], hv, acc[q][2]);
          acc[q][3] = fma(wr[q*4+3], hv, acc[q][3]);
        }
        const double* we = Weg + (u0+j)*4;
        epacc[0] = fma(we[0], hv, epacc[0]);
        epacc[1] = fma(we[1], hv, epacc[1]);
        epacc[2] = fma(we[2], hv, epacc[2]);
        epacc[3] = fma(we[3], hv, epacc[3]);
      }
    }
    #pragma unroll
    for (int q = 0; q < 4; ++q) {
      sm.gred[w][q][lane][0] = acc[q][0];
      sm.gred[w][q][lane][1] = acc[q][1];
      sm.gred[w][q][lane][2] = acc[q][2];
      sm.gred[w][q][lane][3] = acc[q][3];
    }
    #pragma unroll
    for (int k = 0; k < 4; ++k) sm.ered[w][lane][k] = epacc[k];
    __syncthreads();
    {
      double gi = sm.gred[0][w][lane][0] + sm.gred[1][w][lane][0] +
                  sm.gred[2][w][lane][0] + sm.gred[3][w][lane][0];
      double gf = sm.gred[0][w][lane][1] + sm.gred[1][w][lane][1] +
                  sm.gred[2][w][lane][1] + sm.gred[3][w][lane][1];
      double gg = sm.gred[0][w][lane][2] + sm.gred[1][w][lane][2] +
                  sm.gred[2][w][lane][2] + sm.gred[3][w][lane][2];
      double go = sm.gred[0][w][lane][3] + sm.gred[1][w][lane][3] +
                  sm.gred[2][w][lane][3] + sm.gred[3][w][lane][3];
      const double* wx = WxbE + (4*r + w)*16;
      const double x0 = (double)xT[t*1024 + (bG+lane)*2 + 0];
      const double x1 = (double)xT[t*1024 + (bG+lane)*2 + 1];
      gi += fma(wx[0], x0, fma(wx[1], x1, wx[8]));
      gf += fma(wx[2], x0, fma(wx[3], x1, wx[9]));
      gg += fma(wx[4], x0, fma(wx[5], x1, wx[10]));
      go += fma(wx[6], x0, fma(wx[7], x1, wx[11]));
      const double cn = sigmoid_d(gf)*c_state + sigmoid_d(gi)*tanh(gg);
      const double hn = sigmoid_d(go)*tanh(cn);
      c_state = cn;
      hdst[(4*r + w)*512 + bG + lane] = hn;
    }
    if (t > 0) {  // ep[t-1] = We*h^(t) + be, f64
      const int b2 = tid >> 2, kk = tid & 3;
      const double e = sm.ered[0][b2][kk] + sm.ered[1][b2][kk] +
                       sm.ered[2][b2][kk] + sm.ered[3][b2][kk] + be_r;
      ep[(size_t)(bG + b2)*25600 + (t-1)*256 + 4*r + kk] = e;
    }
    ++epoch; group_barrier(flags, rel, g, r, epoch);
  }

  // ep[99] tail on h^(100) (parity 0)
  {
    const double* hsrc = hbuf;
    double epacc[4] = {0.0, 0.0, 0.0, 0.0};
    for (int jc = 0; jc < 4; ++jc) {
      const int u0 = w*64 + jc*16;
      double hreg[16];
      #pragma unroll
      for (int j = 0; j < 16; ++j) hreg[j] = hsrc[(u0+j)*512 + bG + lane];
      #pragma unroll
      for (int j = 0; j < 16; ++j) {
        const double hv = hreg[j];
        const double* we = Weg + (u0+j)*4;
        epacc[0] = fma(we[0], hv, epacc[0]);
        epacc[1] = fma(we[1], hv, epacc[1]);
        epacc[2] = fma(we[2], hv, epacc[2]);
        epacc[3] = fma(we[3], hv, epacc[3]);
      }
    }
    #pragma unroll
    for (int k = 0; k < 4; ++k) sm.ered[w][lane][k] = epacc[k];
    __syncthreads();
    const int b2 = tid >> 2, kk = tid & 3;
    const double e = sm.ered[0][b2][kk] + sm.ered[1][b2][kk] +
                     sm.ered[2][b2][kk] + sm.ered[3][b2][kk] + be_r;
    ep[(size_t)(bG + b2)*25600 + 99*256 + 4*r + kk] = e;
    ++epoch; group_barrier(flags, rel, g, r, epoch);
  }

  // ===================== decoder =====================
  const double vw_r = (double)Vw[tid];
  const double* myep = ep + (size_t)myb*25600 + tid;
  unsigned long long m0 = 0ull, m1 = 0ull;
  float lp_acc = 0.0f;

  for (int t = 0; t < 100; ++t) {
    const double* hsrc = hbuf + (t & 1) * 131072;
    double*       hdst = hbuf + ((t + 1) & 1) * 131072;
    // ---------- (a) decoder LSTM cell ----------
    {
      double acc[4][4] = {};
      for (int jc = 0; jc < 4; ++jc) {
        const int u0 = w*64 + jc*16;
        double hreg[16];
        #pragma unroll
        for (int j = 0; j < 16; ++j) hreg[j] = hsrc[(u0+j)*512 + bG + lane];
        #pragma unroll
        for (int j = 0; j < 16; ++j) {
          const double hv = hreg[j];
          const double* wr = Wg_d + (u0+j)*16;
          #pragma unroll
          for (int q = 0; q < 4; ++q) {
            acc[q][0] = fma(wr[q*4+0], hv, acc[q][0]);
            acc[q][1] = fma(wr[q*4+1], hv, acc[q][1]);
            acc[q][2] = fma(wr[q*4+2], hv, acc[q][2]);
            acc[q][3] = fma(wr[q*4+3], hv, acc[q][3]);
          }
        }
      }
      #pragma unroll
      for (int q = 0; q < 4; ++q) {
        sm.gred[w][q][lane][0] = acc[q][0];
        sm.gred[w][q][lane][1] = acc[q][1];
        sm.gred[w][q][lane][2] = acc[q][2];
        sm.gred[w][q][lane][3] = acc[q][3];
      }
      __syncthreads();
      double gi = sm.gred[0][w][lane][0] + sm.gred[1][w][lane][0] +
                  sm.gred[2][w][lane][0] + sm.gred[3][w][lane][0];
      double gf = sm.gred[0][w][lane][1] + sm.gred[1][w][lane][1] +
                  sm.gred[2][w][lane][1] + sm.gred[3][w][lane][1];
      double gg = sm.gred[0][w][lane][2] + sm.gred[1][w][lane][2] +
                  sm.gred[2][w][lane][2] + sm.gred[3][w][lane][2];
      double go = sm.gred[0][w][lane][3] + sm.gred[1][w][lane][3] +
                  sm.gred[2][w][lane][3] + sm.gred[3][w][lane][3];
      const double* wx = WxbD + (4*r + w)*16;
      const double x0 = (double)din[(bG+lane)*2 + 0];
      const double x1 = (double)din[(bG+lane)*2 + 1];
      gi += fma(wx[0], x0, fma(wx[1], x1, wx[8]));
      gf += fma(wx[2], x0, fma(wx[3], x1, wx[9]));
      gg += fma(wx[4], x0, fma(wx[5], x1, wx[10]));
      go += fma(wx[6], x0, fma(wx[7], x1, wx[11]));
      const double cn = sigmoid_d(gf)*c_state + sigmoid_d(gi)*tanh(gg);
      const double hn = sigmoid_d(go)*tanh(cn);
      c_state = cn;
      hdst[(4*r + w)*512 + bG + lane] = hn;
    }
    ++epoch; group_barrier(flags, rel, g, r, epoch);
    // ---------- (b) dec_proj, f64 ----------
    {
      double dacc[4] = {0.0, 0.0, 0.0, 0.0};
      for (int jc = 0; jc < 4; ++jc) {
        const int u0 = w*64 + jc*16;
        double hreg[16];
        #pragma unroll
        for (int j = 0; j < 16; ++j) hreg[j] = hdst[(u0+j)*512 + bG + lane];
        #pragma unroll
        for (int j = 0; j < 16; ++j) {
          const double hv = hreg[j];
          const double* wr = Wdg + (u0+j)*4;
          dacc[0] = fma(wr[0], hv, dacc[0]);
          dacc[1] = fma(wr[1], hv, dacc[1]);
          dacc[2] = fma(wr[2], hv, dacc[2]);
          dacc[3] = fma(wr[3], hv, dacc[3]);
        }
      }
      #pragma unroll
      for (int k = 0; k < 4; ++k) sm.ered[w][lane][k] = dacc[k];
      __syncthreads();
      const int b2 = tid >> 2, kk = tid & 3;
      const double dv = sm.ered[0][b2][kk] + sm.ered[1][b2][kk] +
                        sm.ered[2][b2][kk] + sm.ered[3][b2][kk] + bd_r;
      dpw[(bG + b2)*256 + 4*r + kk] = dv;
    }
    ++epoch; group_barrier(flags, rel, g, r, epoch);
    // ---------- (c) f64-exact scores -> np-faithful fp32 log_softmax ----------
    {
      const double dpl = dpw[myb*256 + tid];
      for (int s = 0; s < 100; ++s) {
        const bool masked = (s < 64) ? (((m0 >> s) & 1ull) != 0ull)
                                     : (((m1 >> (s-64)) & 1ull) != 0ull);
        if (!masked) {   // block-uniform -> whole-wave skip
          double p = tanh(myep[s*256] + dpl) * vw_r;
          p = wave64_sum_d(p);
          if (lane == 0) sm.sred[s][w] = p;
        }
      }
      __syncthreads();
      if (tid < 100) {
        const bool masked = (tid < 64) ? (((m0 >> tid) & 1ull) != 0ull)
                                       : (((m1 >> (tid-64)) & 1ull) != 0ull);
        // single rounding of the exact score to fp32 (reference dtype)
        sm.scores[tid] = masked ? -__builtin_inff()
                                : (float)(sm.sred[tid][0] + sm.sred[tid][1] +
                                          sm.sred[tid][2] + sm.sred[tid][3] + vb0);
      }
      __syncthreads();
      if (w == 0) {   // m = max(scores), fp32
        const float v0 = sm.scores[lane];
        const float v1 = (lane < 36) ? sm.scores[64 + lane] : -__builtin_inff();
        float mv = fmaxf(v0, v1);
        #pragma unroll
        for (int mm = 1; mm < 64; mm <<= 1)
          mv = fmaxf(mv, __shfl_xor(mv, mm, 64));
        if (lane == 0) sm.red_m = mv;
      }
      __syncthreads();
      if (tid < 100)
        sm.evals[tid] = expf(__fsub_rn(sm.scores[tid], sm.red_m));
      __syncthreads();
      if (tid == 0) {
        // numpy pairwise_sum for n=100: 8 accumulators over 0..95,
        // combine ((r0+r1)+(r2+r3))+((r4+r5)+(r6+r7)), sequential tail 96..99
        float rr[8];
        #pragma unroll
        for (int j = 0; j < 8; ++j) rr[j] = sm.evals[j];
        for (int i = 8; i < 96; i += 8) {
          #pragma unroll
          for (int j = 0; j < 8; ++j) rr[j] = __fadd_rn(rr[j], sm.evals[i + j]);
        }
        float res = __fadd_rn(
            __fadd_rn(__fadd_rn(rr[0], rr[1]), __fadd_rn(rr[2], rr[3])),
            __fadd_rn(__fadd_rn(rr[4], rr[5]), __fadd_rn(rr[6], rr[7])));
        res = __fadd_rn(res, sm.evals[96]);
        res = __fadd_rn(res, sm.evals[97]);
        res = __fadd_rn(res, sm.evals[98]);
        res = __fadd_rn(res, sm.evals[99]);
        sm.red_L = logf(res);
      }
      __syncthreads();
      if (w == 0) {   // lp = fl(fl(s - m) - L); argmax(lp), first index on ties
        const float m = sm.red_m, L = sm.red_L;
        const float lp0 = __fsub_rn(__fsub_rn(sm.scores[lane], m), L);
        const float lp1 = (lane < 36)
            ? __fsub_rn(__fsub_rn(sm.scores[64 + lane], m), L)
            : -__builtin_inff();
        float bv; int bi;
        if (lp0 >= lp1) { bv = lp0; bi = lane; } else { bv = lp1; bi = 64 + lane; }
        #pragma unroll
        for (int mm = 1; mm < 64; mm <<= 1) {
          const float ov = __shfl_xor(bv, mm, 64);
          const int   oi = __shfl_xor(bi, mm, 64);
          if (ov > bv || (ov == bv && oi < bi)) { bv = ov; bi = oi; }
        }
        if (lane == 0) { sm.bc_sel = bi; sm.bc_lp = bv; }
      }
      __syncthreads();
      const int sel = __builtin_amdgcn_readfirstlane(sm.bc_sel);
      lp_acc = __fadd_rn(lp_acc, sm.bc_lp);   // np axis-0 sum: sequential fp32
      if (sel < 64) m0 |= (1ull << sel); else m1 |= (1ull << (sel - 64));
      if (tid == 0) out[myb*100 + t] = (float)sel;
      if (tid < 2) din[myb*2 + tid] = xT[sel*1024 + myb*2 + tid];
    }
    ++epoch; group_barrier(flags, rel, g, r, epoch);
  }

  // ---------------- outputs ----------------
  if (tid == 0) out[51200 + myb] = lp_acc;
  out[51712 + myb*256 + tid] = (float)hbuf[tid*512 + myb];  // final h (parity 0)
}

extern "C" void kernel_launch(void* const* d_in, const int* in_sizes, int n_in,
                              void* d_out, int out_size, void* d_ws, size_t ws_size,
                              hipStream_t stream) {
  const float* x     = (const float*)d_in[0];
  const float* eWih  = (const float*)d_in[1];
  const float* eWhh  = (const float*)d_in[2];
  const float* ebih  = (const float*)d_in[3];
  const float* ebhh  = (const float*)d_in[4];
  const float* dWih  = (const float*)d_in[5];
  const float* dWhh  = (const float*)d_in[6];
  const float* dbih  = (const float*)d_in[7];
  const float* dbhh  = (const float*)d_in[8];
  const float* We    = (const float*)d_in[9];
  const float* be    = (const float*)d_in[10];
  const float* Wd    = (const float*)d_in[11];
  const float* bd    = (const float*)d_in[12];
  const float* vw    = (const float*)d_in[13];
  const float* vb    = (const float*)d_in[14];
  const float* start = (const float*)d_in[15];
  char* ws    = (char*)d_ws;
  float* outp = (float*)d_out;

  ptrnet_prep<<<dim3(512), dim3(256), 0, stream>>>(
      x, eWih, eWhh, ebih, ebhh, dWih, dWhh, dbih, dbhh, We, Wd, start, ws);

  ptrnet_main<<<dim3(512), dim3(256), 0, stream>>>(ws, be, bd, vw, vb, outp);
}

// Round 8
// 23241.039 us; speedup vs baseline: 1.1886x; 1.1886x over previous
//
#include <hip/hip_runtime.h>

// Pointer network: encoder LSTM -> enc_proj -> decoder LSTM + attention argmax.
// B=512, S=100, D=2, H=256.
//
// NUMERICS (FROZEN as of R7, absmax 7.0 <= 7.2 -- do not touch):
//   TRAJECTORY = fp64 state evolution (h/c/gates/ep/dp f64, same orders as R7).
//   SELECTION  = np-faithful fp32 log_softmax: scores rounded to fp32 once;
//   m=max; shifted=__fsub_rn; E=expf; sum(E) in numpy pairwise order (8 accs
//   over 0..95, ((r0+r1)+(r2+r3))+((r4+r5)+(r6+r7)), sequential tail 96..99);
//   L=logf; lp=__fsub_rn(shifted,L); argmax(lp) first-index tie-break; lp_acc
//   sequential fp32.
//
// R8 change (structure only): barrier de-fencing. R7 polled with AGENT-scope
// ACQUIRE loads -> per-poll L1/L2 invalidate + writeback on gfx9 multi-XCD ->
// L2 evicted dozens of times per barrier x 401 barriers -> FETCH_SIZE 3.7GB,
// ~57us stall/phase, VALUBusy 17%. New barrier: arrival via fetch_add RMW
// (coherence-point, stale-L2-immune), relaxed polls (acquire fallback after 64
// spins for hang-safety), exactly ONE __threadfence() per side per barrier.
//
// 512 blocks x 256 threads, plain launch; co-residency via
// __launch_bounds__(256,2) + ~45KB LDS -> exactly 2 blocks/CU x 256 CUs.
// group g = bid&7 (all 64 blocks of a group land on one XCD via round-robin
// dispatch -> group traffic is XCD-local), role r = bid>>3.

#define B_WENC 0ull
#define B_WDEC (B_WENC + 1024ull*256ull*8ull)
#define B_WE   (B_WDEC + 1024ull*256ull*8ull)
#define B_WD   (B_WE   + 256ull*256ull*8ull)
#define B_WXE  (B_WD   + 256ull*256ull*8ull)
#define B_WXD  (B_WXE  + 256ull*16ull*8ull)
#define B_H    (B_WXD  + 256ull*16ull*8ull)
#define B_XT   (B_H    + 2ull*256ull*512ull*8ull)
#define B_DIN  (B_XT   + 100ull*512ull*2ull*4ull)
#define B_DP   (B_DIN  + 512ull*2ull*4ull)
#define B_EP   (B_DP   + 512ull*256ull*8ull)
#define B_SYNC (B_EP   + 512ull*100ull*256ull*8ull)

__device__ __forceinline__ double sigmoid_d(double x) {
  return 1.0 / (1.0 + exp(-x));
}

__device__ __forceinline__ double shfl_xor_d(double v, int m) {
  const long long l = __double_as_longlong(v);
  int lo = (int)(l & 0xffffffffll), hi = (int)(l >> 32);
  lo = __shfl_xor(lo, m, 64);
  hi = __shfl_xor(hi, m, 64);
  return __longlong_as_double(((long long)hi << 32) | (unsigned int)lo);
}

__device__ __forceinline__ double wave64_sum_d(double v) {
  #pragma unroll
  for (int m = 1; m < 64; m <<= 1) v += shfl_xor_d(v, m);
  return v;
}

// Group barrier, de-fenced hot path:
//  - arrival: fetch_add(1) RMW -> executes at the coherence point (works even
//    though per-XCD L2s are not cross-coherent).
//  - polls: RELAXED atomic loads (no per-poll cache maintenance). After 64
//    spins fall back to ACQUIRE loads so progress is guaranteed even if
//    relaxed agent loads were served from a stale local L2.
//  - data transport: exactly one __threadfence() (wb) before arrival and one
//    (inv) after the wait. These are the only cache-maintenance ops.
__device__ __forceinline__ void group_barrier(int* flags, int* rel, int g, int r,
                                              int epoch) {
  __syncthreads();
  const int tid = threadIdx.x;
  if (tid == 0) {
    __threadfence();  // release: one L2 writeback; block's h/ep/dp now visible
    __hip_atomic_fetch_add(&flags[g*64 + r], 1, __ATOMIC_RELAXED,
                           __HIP_MEMORY_SCOPE_AGENT);
  }
  if (r == 0) {
    if (tid < 64) {
      for (int spin = 0;; ++spin) {
        const int v = (spin < 64)
            ? __hip_atomic_load(&flags[g*64 + tid], __ATOMIC_RELAXED,
                                __HIP_MEMORY_SCOPE_AGENT)
            : __hip_atomic_load(&flags[g*64 + tid], __ATOMIC_ACQUIRE,
                                __HIP_MEMORY_SCOPE_AGENT);
        if (__all(v >= epoch)) break;
        __builtin_amdgcn_s_sleep(8);
      }
      if (tid == 0)
        __hip_atomic_fetch_add(&rel[g*32], 1, __ATOMIC_RELAXED,
                               __HIP_MEMORY_SCOPE_AGENT);
    }
  } else if (tid == 0) {
    for (int spin = 0;; ++spin) {
      const int v = (spin < 64)
          ? __hip_atomic_load(&rel[g*32], __ATOMIC_RELAXED,
                              __HIP_MEMORY_SCOPE_AGENT)
          : __hip_atomic_load(&rel[g*32], __ATOMIC_ACQUIRE,
                              __HIP_MEMORY_SCOPE_AGENT);
      if (v >= epoch) break;
      __builtin_amdgcn_s_sleep(8);
    }
  }
  if (tid == 0) __threadfence();  // acquire: one L2 invalidate; see peers' data
  __syncthreads();
}

struct SMem {
  double gred[4][4][64][4];  // [writer wave][unit][b][gate]  32 KB
  double ered[4][64][4];     // [writer wave][b][kk]           8 KB
  double sred[100][4];       // per-s per-wave f64 partials   3.2 KB
  float  scores[104];
  float  evals[104];
  float  red_m, red_L;
  float  bc_lp;
  int    bc_sel;
};

extern "C" __global__ void ptrnet_prep(
    const float* __restrict__ x,
    const float* __restrict__ eWih, const float* __restrict__ eWhh,
    const float* __restrict__ ebih, const float* __restrict__ ebhh,
    const float* __restrict__ dWih, const float* __restrict__ dWhh,
    const float* __restrict__ dbih, const float* __restrict__ dbhh,
    const float* __restrict__ We,  const float* __restrict__ Wd,
    const float* __restrict__ start, char* __restrict__ wsb)
{
  const int idx = blockIdx.x * blockDim.x + threadIdx.x;
  const int stride = gridDim.x * blockDim.x;
  double* WENC = (double*)(wsb + B_WENC);
  double* WDEC = (double*)(wsb + B_WDEC);
  double* WEd  = (double*)(wsb + B_WE);
  double* WDd  = (double*)(wsb + B_WD);
  double* WXE  = (double*)(wsb + B_WXE);
  double* WXD  = (double*)(wsb + B_WXD);
  double* Hd   = (double*)(wsb + B_H);
  float*  XT   = (float*)(wsb + B_XT);
  float*  DIN  = (float*)(wsb + B_DIN);
  int*    SY   = (int*)(wsb + B_SYNC);

  // Whh -> [r][u][uu][gate] in f64
  for (int i = idx; i < 1024*256; i += stride) {
    const int gate = i & 3, uu = (i >> 2) & 3, u = (i >> 4) & 255, rr = i >> 12;
    const int row = gate*256 + rr*4 + uu;
    WENC[i] = (double)eWhh[row*256 + u];
    WDEC[i] = (double)dWhh[row*256 + u];
  }
  // att_We / att_Wd -> [r][u][kk] in f64
  for (int i = idx; i < 256*256; i += stride) {
    const int kk = i & 3, u = (i >> 2) & 255, rr = i >> 10;
    const int row = rr*4 + kk;
    WEd[i] = (double)We[row*256 + u];
    WDd[i] = (double)Wd[row*256 + u];
  }
  // Wih + bias pack: [u][16] = {i0,i1,f0,f1,g0,g1,o0,o1, bi,bf,bg,bo, pad}
  for (int i = idx; i < 256*16; i += stride) {
    const int f = i & 15, u = i >> 4;
    double ve = 0.0, vd = 0.0;
    if (f < 8) {
      const int gg = f >> 1, d = f & 1;
      ve = (double)eWih[(gg*256+u)*2 + d];
      vd = (double)dWih[(gg*256+u)*2 + d];
    } else if (f < 12) {
      const int gg = f - 8;
      ve = (double)ebih[gg*256+u] + (double)ebhh[gg*256+u];
      vd = (double)dbih[gg*256+u] + (double)dbhh[gg*256+u];
    }
    WXE[i] = ve;
    WXD[i] = vd;
  }
  // x -> [t][b][d] (f32: exact values)
  for (int i = idx; i < 100*512*2; i += stride) {
    const int d = i & 1, b = (i >> 1) & 511, t = i >> 10;
    XT[i] = x[(b*100 + t)*2 + d];
  }
  for (int i = idx; i < 2*256*512; i += stride) Hd[i] = 0.0;
  for (int i = idx; i < 1024; i += stride) DIN[i] = start[i & 1];
  for (int i = idx; i < 1024; i += stride) SY[i] = 0;
}

extern "C" __global__ void __launch_bounds__(256, 2)
ptrnet_main(char* __restrict__ wsb,
            const float* __restrict__ att_be,
            const float* __restrict__ att_bd,
            const float* __restrict__ Vw,
            const float* __restrict__ Vb,
            float* __restrict__ out)
{
  __shared__ SMem sm;
  const int bid = blockIdx.x;
  const int g   = bid & 7;
  const int r   = bid >> 3;
  const int tid = threadIdx.x;
  const int lane = tid & 63;
  const int w = __builtin_amdgcn_readfirstlane(tid >> 6);
  const int bG = g * 64;
  const int myb = bG + r;

  double* hbuf = (double*)(wsb + B_H);
  float*  xT   = (float*)(wsb + B_XT);
  float*  din  = (float*)(wsb + B_DIN);
  double* dpw  = (double*)(wsb + B_DP);
  double* ep   = (double*)(wsb + B_EP);
  int* flags   = (int*)(wsb + B_SYNC);
  int* rel     = flags + 512;

  const double* Wg_e = (double*)(wsb + B_WENC) + r*(256*16);
  const double* Wg_d = (double*)(wsb + B_WDEC) + r*(256*16);
  const double* Weg  = (double*)(wsb + B_WE)   + r*(256*4);
  const double* Wdg  = (double*)(wsb + B_WD)   + r*(256*4);
  const double* WxbE = (double*)(wsb + B_WXE);
  const double* WxbD = (double*)(wsb + B_WXD);

  const double be_r = (double)att_be[4*r + (tid & 3)];
  const double bd_r = (double)att_bd[4*r + (tid & 3)];
  const double vb0  = (double)Vb[0];

  int epoch = 0;
  double c_state = 0.0;

  // ============================ encoder ============================
  for (int t = 0; t < 100; ++t) {
    const double* hsrc = hbuf + (t & 1) * 131072;
    double*       hdst = hbuf + ((t + 1) & 1) * 131072;
    double acc[4][4] = {};
    double epacc[4] = {0.0, 0.0, 0.0, 0.0};
    for (int jc = 0; jc < 4; ++jc) {
      const int u0 = w*64 + jc*16;
      double hreg[16];
      #pragma unroll
      for (int j = 0; j < 16; ++j) hreg[j] = hsrc[(u0+j)*512 + bG + lane];
      #pragma unroll
      for (int j = 0; j < 16; ++j) {
        const double hv = hreg[j];
        const double* wr = Wg_e + (u0+j)*16;
        #pragma unroll
        for (int q = 0; q < 4; ++q) {
          acc[q][0] = fma(wr[q*4+0], hv, acc[q][0]);
          acc[q][1] = fma(wr[q*4+1], hv, acc[q][1]);
          acc[q][2] = fma(wr[q*4+2], hv, acc[q][2]);
          acc[q][3] = fma(wr[q*4+3], hv, acc[q][3]);
        }
        const double* we = Weg + (u0+j)*4;
        epacc[0] = fma(we[0], hv, epacc[0]);
        epacc[1] = fma(we[1], hv, epacc[1]);
        epacc[2] = fma(we[2], hv, epacc[2]);
        epacc[3] = fma(we[3], hv, epacc[3]);
      }
    }
    #pragma unroll
    for (int q = 0; q < 4; ++q) {
      sm.gred[w][q][lane][0] = acc[q][0];
      sm.gred[w][q][lane][1] = acc[q][1];
      sm.gred[w][q][lane][2] = acc[q][2];
      sm.gred[w][q][lane][3] = acc[q][3];
    }
    #pragma unroll
    for (int k = 0; k < 4; ++k) sm.ered[w][lane][k] = epacc[k];
    __syncthreads();
    {
      double gi = sm.gred[0][w][lane][0] + sm.gred[1][w][lane][0] +
                  sm.gred[2][w][lane][0] + sm.gred[3][w][lane][0];
      double gf = sm.gred[0][w][lane][1] + sm.gred[1][w][lane][1] +
                  sm.gred[2][w][lane][1] + sm.gred[3][w][lane][1];
      double gg = sm.gred[0][w][lane][2] + sm.gred[1][w][lane][2] +
                  sm.gred[2][w][lane][2] + sm.gred[3][w][lane][2];
      double go = sm.gred[0][w][lane][3] + sm.gred[1][w][lane][3] +
                  sm.gred[2][w][lane][3] + sm.gred[3][w][lane][3];
      const double* wx = WxbE + (4*r + w)*16;
      const double x0 = (double)xT[t*1024 + (bG+lane)*2 + 0];
      const double x1 = (double)xT[t*1024 + (bG+lane)*2 + 1];
      gi += fma(wx[0], x0, fma(wx[1], x1, wx[8]));
      gf += fma(wx[2], x0, fma(wx[3], x1, wx[9]));
      gg += fma(wx[4], x0, fma(wx[5], x1, wx[10]));
      go += fma(wx[6], x0, fma(wx[7], x1, wx[11]));
      const double cn = sigmoid_d(gf)*c_state + sigmoid_d(gi)*tanh(gg);
      const double hn = sigmoid_d(go)*tanh(cn);
      c_state = cn;
      hdst[(4*r + w)*512 + bG + lane] = hn;
    }
    if (t > 0) {  // ep[t-1] = We*h^(t) + be, f64
      const int b2 = tid >> 2, kk = tid & 3;
      const double e = sm.ered[0][b2][kk] + sm.ered[1][b2][kk] +
                       sm.ered[2][b2][kk] + sm.ered[3][b2][kk] + be_r;
      ep[(size_t)(bG + b2)*25600 + (t-1)*256 + 4*r + kk] = e;
    }
    ++epoch; group_barrier(flags, rel, g, r, epoch);
  }

  // ep[99] tail on h^(100) (parity 0)
  {
    const double* hsrc = hbuf;
    double epacc[4] = {0.0, 0.0, 0.0, 0.0};
    for (int jc = 0; jc < 4; ++jc) {
      const int u0 = w*64 + jc*16;
      double hreg[16];
      #pragma unroll
      for (int j = 0; j < 16; ++j) hreg[j] = hsrc[(u0+j)*512 + bG + lane];
      #pragma unroll
      for (int j = 0; j < 16; ++j) {
        const double hv = hreg[j];
        const double* we = Weg + (u0+j)*4;
        epacc[0] = fma(we[0], hv, epacc[0]);
        epacc[1] = fma(we[1], hv, epacc[1]);
        epacc[2] = fma(we[2], hv, epacc[2]);
        epacc[3] = fma(we[3], hv, epacc[3]);
      }
    }
    #pragma unroll
    for (int k = 0; k < 4; ++k) sm.ered[w][lane][k] = epacc[k];
    __syncthreads();
    const int b2 = tid >> 2, kk = tid & 3;
    const double e = sm.ered[0][b2][kk] + sm.ered[1][b2][kk] +
                     sm.ered[2][b2][kk] + sm.ered[3][b2][kk] + be_r;
    ep[(size_t)(bG + b2)*25600 + 99*256 + 4*r + kk] = e;
    ++epoch; group_barrier(flags, rel, g, r, epoch);
  }

  // ===================== decoder =====================
  const double vw_r = (double)Vw[tid];
  const double* myep = ep + (size_t)myb*25600 + tid;
  unsigned long long m0 = 0ull, m1 = 0ull;
  float lp_acc = 0.0f;

  for (int t = 0; t < 100; ++t) {
    const double* hsrc = hbuf + (t & 1) * 131072;
    double*       hdst = hbuf + ((t + 1) & 1) * 131072;
    // ---------- (a) decoder LSTM cell ----------
    {
      double acc[4][4] = {};
      for (int jc = 0; jc < 4; ++jc) {
        const int u0 = w*64 + jc*16;
        double hreg[16];
        #pragma unroll
        for (int j = 0; j < 16; ++j) hreg[j] = hsrc[(u0+j)*512 + bG + lane];
        #pragma unroll
        for (int j = 0; j < 16; ++j) {
          const double hv = hreg[j];
          const double* wr = Wg_d + (u0+j)*16;
          #pragma unroll
          for (int q = 0; q < 4; ++q) {
            acc[q][0] = fma(wr[q*4+0], hv, acc[q][0]);
            acc[q][1] = fma(wr[q*4+1], hv, acc[q][1]);
            acc[q][2] = fma(wr[q*4+2], hv, acc[q][2]);
            acc[q][3] = fma(wr[q*4+3], hv, acc[q][3]);
          }
        }
      }
      #pragma unroll
      for (int q = 0; q < 4; ++q) {
        sm.gred[w][q][lane][0] = acc[q][0];
        sm.gred[w][q][lane][1] = acc[q][1];
        sm.gred[w][q][lane][2] = acc[q][2];
        sm.gred[w][q][lane][3] = acc[q][3];
      }
      __syncthreads();
      double gi = sm.gred[0][w][lane][0] + sm.gred[1][w][lane][0] +
                  sm.gred[2][w][lane][0] + sm.gred[3][w][lane][0];
      double gf = sm.gred[0][w][lane][1] + sm.gred[1][w][lane][1] +
                  sm.gred[2][w][lane][1] + sm.gred[3][w][lane][1];
      double gg = sm.gred[0][w][lane][2] + sm.gred[1][w][lane][2] +
                  sm.gred[2][w][lane][2] + sm.gred[3][w][lane][2];
      double go = sm.gred[0][w][lane][3] + sm.gred[1][w][lane][3] +
                  sm.gred[2][w][lane][3] + sm.gred[3][w][lane][3];
      const double* wx = WxbD + (4*r + w)*16;
      const double x0 = (double)din[(bG+lane)*2 + 0];
      const double x1 = (double)din[(bG+lane)*2 + 1];
      gi += fma(wx[0], x0, fma(wx[1], x1, wx[8]));
      gf += fma(wx[2], x0, fma(wx[3], x1, wx[9]));
      gg += fma(wx[4], x0, fma(wx[5], x1, wx[10]));
      go += fma(wx[6], x0, fma(wx[7], x1, wx[11]));
      const double cn = sigmoid_d(gf)*c_state + sigmoid_d(gi)*tanh(gg);
      const double hn = sigmoid_d(go)*tanh(cn);
      c_state = cn;
      hdst[(4*r + w)*512 + bG + lane] = hn;
    }
    ++epoch; group_barrier(flags, rel, g, r, epoch);
    // ---------- (b) dec_proj, f64 ----------
    {
      double dacc[4] = {0.0, 0.0, 0.0, 0.0};
      for (int jc = 0; jc < 4; ++jc) {
        const int u0 = w*64 + jc*16;
        double hreg[16];
        #pragma unroll
        for (int j = 0; j < 16; ++j) hreg[j] = hdst[(u0+j)*512 + bG + lane];
        #pragma unroll
        for (int j = 0; j < 16; ++j) {
          const double hv = hreg[j];
          const double* wr = Wdg + (u0+j)*4;
          dacc[0] = fma(wr[0], hv, dacc[0]);
          dacc[1] = fma(wr[1], hv, dacc[1]);
          dacc[2] = fma(wr[2], hv, dacc[2]);
          dacc[3] = fma(wr[3], hv, dacc[3]);
        }
      }
      #pragma unroll
      for (int k = 0; k < 4; ++k) sm.ered[w][lane][k] = dacc[k];
      __syncthreads();
      const int b2 = tid >> 2, kk = tid & 3;
      const double dv = sm.ered[0][b2][kk] + sm.ered[1][b2][kk] +
                        sm.ered[2][b2][kk] + sm.ered[3][b2][kk] + bd_r;
      dpw[(bG + b2)*256 + 4*r + kk] = dv;
    }
    ++epoch; group_barrier(flags, rel, g, r, epoch);
    // ---------- (c) f64-exact scores -> np-faithful fp32 log_softmax ----------
    {
      const double dpl = dpw[myb*256 + tid];
      for (int s = 0; s < 100; ++s) {
        const bool masked = (s < 64) ? (((m0 >> s) & 1ull) != 0ull)
                                     : (((m1 >> (s-64)) & 1ull) != 0ull);
        if (!masked) {   // block-uniform -> whole-wave skip
          double p = tanh(myep[s*256] + dpl) * vw_r;
          p = wave64_sum_d(p);
          if (lane == 0) sm.sred[s][w] = p;
        }
      }
      __syncthreads();
      if (tid < 100) {
        const bool masked = (tid < 64) ? (((m0 >> tid) & 1ull) != 0ull)
                                       : (((m1 >> (tid-64)) & 1ull) != 0ull);
        // single rounding of the exact score to fp32 (reference dtype)
        sm.scores[tid] = masked ? -__builtin_inff()
                                : (float)(sm.sred[tid][0] + sm.sred[tid][1] +
                                          sm.sred[tid][2] + sm.sred[tid][3] + vb0);
      }
      __syncthreads();
      if (w == 0) {   // m = max(scores), fp32
        const float v0 = sm.scores[lane];
        const float v1 = (lane < 36) ? sm.scores[64 + lane] : -__builtin_inff();
        float mv = fmaxf(v0, v1);
        #pragma unroll
        for (int mm = 1; mm < 64; mm <<= 1)
          mv = fmaxf(mv, __shfl_xor(mv, mm, 64));
        if (lane == 0) sm.red_m = mv;
      }
      __syncthreads();
      if (tid < 100)
        sm.evals[tid] = expf(__fsub_rn(sm.scores[tid], sm.red_m));
      __syncthreads();
      if (tid == 0) {
        // numpy pairwise_sum for n=100: 8 accumulators over 0..95,
        // combine ((r0+r1)+(r2+r3))+((r4+r5)+(r6+r7)), sequential tail 96..99
        float rr[8];
        #pragma unroll
        for (int j = 0; j < 8; ++j) rr[j] = sm.evals[j];
        for (int i = 8; i < 96; i += 8) {
          #pragma unroll
          for (int j = 0; j < 8; ++j) rr[j] = __fadd_rn(rr[j], sm.evals[i + j]);
        }
        float res = __fadd_rn(
            __fadd_rn(__fadd_rn(rr[0], rr[1]), __fadd_rn(rr[2], rr[3])),
            __fadd_rn(__fadd_rn(rr[4], rr[5]), __fadd_rn(rr[6], rr[7])));
        res = __fadd_rn(res, sm.evals[96]);
        res = __fadd_rn(res, sm.evals[97]);
        res = __fadd_rn(res, sm.evals[98]);
        res = __fadd_rn(res, sm.evals[99]);
        sm.red_L = logf(res);
      }
      __syncthreads();
      if (w == 0) {   // lp = fl(fl(s - m) - L); argmax(lp), first index on ties
        const float m = sm.red_m, L = sm.red_L;
        const float lp0 = __fsub_rn(__fsub_rn(sm.scores[lane], m), L);
        const float lp1 = (lane < 36)
            ? __fsub_rn(__fsub_rn(sm.scores[64 + lane], m), L)
            : -__builtin_inff();
        float bv; int bi;
        if (lp0 >= lp1) { bv = lp0; bi = lane; } else { bv = lp1; bi = 64 + lane; }
        #pragma unroll
        for (int mm = 1; mm < 64; mm <<= 1) {
          const float ov = __shfl_xor(bv, mm, 64);
          const int   oi = __shfl_xor(bi, mm, 64);
          if (ov > bv || (ov == bv && oi < bi)) { bv = ov; bi = oi; }
        }
        if (lane == 0) { sm.bc_sel = bi; sm.bc_lp = bv; }
      }
      __syncthreads();
      const int sel = __builtin_amdgcn_readfirstlane(sm.bc_sel);
      lp_acc = __fadd_rn(lp_acc, sm.bc_lp);   // np axis-0 sum: sequential fp32
      if (sel < 64) m0 |= (1ull << sel); else m1 |= (1ull << (sel - 64));
      if (tid == 0) out[myb*100 + t] = (float)sel;
      if (tid < 2) din[myb*2 + tid] = xT[sel*1024 + myb*2 + tid];
    }
    ++epoch; group_barrier(flags, rel, g, r, epoch);
  }

  // ---------------- outputs ----------------
  if (tid == 0) out[51200 + myb] = lp_acc;
  out[51712 + myb*256 + tid] = (float)hbuf[tid*512 + myb];  // final h (parity 0)
}

extern "C" void kernel_launch(void* const* d_in, const int* in_sizes, int n_in,
                              void* d_out, int out_size, void* d_ws, size_t ws_size,
                              hipStream_t stream) {
  const float* x     = (const float*)d_in[0];
  const float* eWih  = (const float*)d_in[1];
  const float* eWhh  = (const float*)d_in[2];
  const float* ebih  = (const float*)d_in[3];
  const float* ebhh  = (const float*)d_in[4];
  const float* dWih  = (const float*)d_in[5];
  const float* dWhh  = (const float*)d_in[6];
  const float* dbih  = (const float*)d_in[7];
  const float* dbhh  = (const float*)d_in[8];
  const float* We    = (const float*)d_in[9];
  const float* be    = (const float*)d_in[10];
  const float* Wd    = (const float*)d_in[11];
  const float* bd    = (const float*)d_in[12];
  const float* vw    = (const float*)d_in[13];
  const float* vb    = (const float*)d_in[14];
  const float* start = (const float*)d_in[15];
  char* ws    = (char*)d_ws;
  float* outp = (float*)d_out;

  ptrnet_prep<<<dim3(512), dim3(256), 0, stream>>>(
      x, eWih, eWhh, ebih, ebhh, dWih, dWhh, dbih, dbhh, We, Wd, start, ws);

  ptrnet_main<<<dim3(512), dim3(256), 0, stream>>>(ws, be, bd, vw, vb, outp);
}

// Round 9
// 17432.933 us; speedup vs baseline: 1.5847x; 1.3332x over previous
//
#include <hip/hip_runtime.h>

// Pointer network: encoder LSTM -> enc_proj -> decoder LSTM + attention argmax.
// B=512, S=100, D=2, H=256.
//
// NUMERICS (FROZEN since R7, absmax 7.0 <= 7.2 -- do not touch):
//   TRAJECTORY = fp64 state evolution (h/c/gates/ep/dp f64, same orders).
//   SELECTION  = np-faithful fp32 log_softmax (pairwise-8 sum, lp quantization
//   tie-break to lower index), lp_acc sequential fp32.
//
// R9 change (structure only): ZERO-FENCE communication. R8 still nuked L2 every
// phase (relaxed polls hit stale L2 lines -> 14us dead-spin -> acquire fallback
// invalidated L2 anyway; FETCH_SIZE stayed 3.7GB = 9MB/phase refill at ~180GB/s
// = the runtime). Now: communicated data (h/ep/dpw/din) uses SYSTEM-scope
// relaxed atomics (sc0+sc1, L2-bypass to the coherence point -- always fresh,
// no cache maintenance); weights/xT are plain cached loads and stay L2-resident
// for all 300 phases (no fence ever executes); barrier = system-scope RMW
// arrival (RELEASE drains sc1 stores; wbl2 of a clean L2 is cheap) + system
// relaxed polls. Also: gred/ered LDS layout [..][gate][lane] (8B lane stride,
// ~2-way) replacing [..][lane][gate] (32B stride, 16-way, 1.79e8 conflicts).
//
// 512 blocks x 256 threads, plain launch; co-residency via
// __launch_bounds__(256,2) + ~45KB LDS -> exactly 2 blocks/CU x 256 CUs.
// group g = bid&7, role r = bid>>3; group owns batch [g*64, g*64+64).

#define B_WENC 0ull
#define B_WDEC (B_WENC + 1024ull*256ull*8ull)
#define B_WE   (B_WDEC + 1024ull*256ull*8ull)
#define B_WD   (B_WE   + 256ull*256ull*8ull)
#define B_WXE  (B_WD   + 256ull*256ull*8ull)
#define B_WXD  (B_WXE  + 256ull*16ull*8ull)
#define B_H    (B_WXD  + 256ull*16ull*8ull)
#define B_XT   (B_H    + 2ull*256ull*512ull*8ull)
#define B_DIN  (B_XT   + 100ull*512ull*2ull*4ull)
#define B_DP   (B_DIN  + 512ull*2ull*4ull)
#define B_EP   (B_DP   + 512ull*256ull*8ull)
#define B_SYNC (B_EP   + 512ull*100ull*256ull*8ull)

__device__ __forceinline__ double sigmoid_d(double x) {
  return 1.0 / (1.0 + exp(-x));
}

// ---- system-scope relaxed accessors: sc0+sc1, bypass the non-coherent L2s,
// ---- no fences, no invalidations. Used ONLY for inter-block communicated data.
__device__ __forceinline__ double ld_sys_d(const double* p) {
  return __hip_atomic_load((double*)p, __ATOMIC_RELAXED,
                           __HIP_MEMORY_SCOPE_SYSTEM);
}
__device__ __forceinline__ void st_sys_d(double* p, double v) {
  __hip_atomic_store(p, v, __ATOMIC_RELAXED, __HIP_MEMORY_SCOPE_SYSTEM);
}
__device__ __forceinline__ float ld_sys_f(const float* p) {
  return __hip_atomic_load((float*)p, __ATOMIC_RELAXED,
                           __HIP_MEMORY_SCOPE_SYSTEM);
}
__device__ __forceinline__ void st_sys_f(float* p, float v) {
  __hip_atomic_store(p, v, __ATOMIC_RELAXED, __HIP_MEMORY_SCOPE_SYSTEM);
}

__device__ __forceinline__ double shfl_xor_d(double v, int m) {
  const long long l = __double_as_longlong(v);
  int lo = (int)(l & 0xffffffffll), hi = (int)(l >> 32);
  lo = __shfl_xor(lo, m, 64);
  hi = __shfl_xor(hi, m, 64);
  return __longlong_as_double(((long long)hi << 32) | (unsigned int)lo);
}

__device__ __forceinline__ double wave64_sum_d(double v) {
  #pragma unroll
  for (int m = 1; m < 64; m <<= 1) v += shfl_xor_d(v, m);
  return v;
}

// Group barrier, zero-cache-maintenance hot path. Arrival: system-scope
// fetch_add(RELEASE) -- drains this block's sc1 data stores before the flag
// becomes visible (wbl2 of a clean L2 ~free; nothing dirty accumulates).
// Polls: system-scope RELAXED loads -- always served by the coherence point
// (fresh), never invalidate anything. Acquire fallback after 1M spins is
// hang insurance only.
__device__ __forceinline__ void group_barrier(int* flags, int* rel, int g, int r,
                                              int epoch) {
  __syncthreads();
  const int tid = threadIdx.x;
  if (tid == 0)
    __hip_atomic_fetch_add(&flags[g*64 + r], 1, __ATOMIC_RELEASE,
                           __HIP_MEMORY_SCOPE_SYSTEM);
  if (r == 0) {
    if (tid < 64) {
      for (int spin = 0;; ++spin) {
        const int v = (spin < (1 << 20))
            ? __hip_atomic_load(&flags[g*64 + tid], __ATOMIC_RELAXED,
                                __HIP_MEMORY_SCOPE_SYSTEM)
            : __hip_atomic_load(&flags[g*64 + tid], __ATOMIC_ACQUIRE,
                                __HIP_MEMORY_SCOPE_SYSTEM);
        if (__all(v >= epoch)) break;
        __builtin_amdgcn_s_sleep(2);
      }
      if (tid == 0)
        __hip_atomic_fetch_add(&rel[g*32], 1, __ATOMIC_RELAXED,
                               __HIP_MEMORY_SCOPE_SYSTEM);
    }
  } else if (tid == 0) {
    for (int spin = 0;; ++spin) {
      const int v = (spin < (1 << 20))
          ? __hip_atomic_load(&rel[g*32], __ATOMIC_RELAXED,
                              __HIP_MEMORY_SCOPE_SYSTEM)
          : __hip_atomic_load(&rel[g*32], __ATOMIC_ACQUIRE,
                              __HIP_MEMORY_SCOPE_SYSTEM);
      if (v >= epoch) break;
      __builtin_amdgcn_s_sleep(2);
    }
  }
  __atomic_signal_fence(__ATOMIC_SEQ_CST);  // compiler-only: pin load order
  __syncthreads();
}

struct SMem {
  double gred[4][4][4][64];  // [writer wave][unit][gate][lane]  32 KB, 8B stride
  double ered[4][4][64];     // [writer wave][kk][lane]           8 KB
  double sred[100][4];       // per-s per-wave f64 partials      3.2 KB
  float  scores[104];
  float  evals[104];
  float  red_m, red_L;
  float  bc_lp;
  int    bc_sel;
};

extern "C" __global__ void ptrnet_prep(
    const float* __restrict__ x,
    const float* __restrict__ eWih, const float* __restrict__ eWhh,
    const float* __restrict__ ebih, const float* __restrict__ ebhh,
    const float* __restrict__ dWih, const float* __restrict__ dWhh,
    const float* __restrict__ dbih, const float* __restrict__ dbhh,
    const float* __restrict__ We,  const float* __restrict__ Wd,
    const float* __restrict__ start, char* __restrict__ wsb)
{
  const int idx = blockIdx.x * blockDim.x + threadIdx.x;
  const int stride = gridDim.x * blockDim.x;
  double* WENC = (double*)(wsb + B_WENC);
  double* WDEC = (double*)(wsb + B_WDEC);
  double* WEd  = (double*)(wsb + B_WE);
  double* WDd  = (double*)(wsb + B_WD);
  double* WXE  = (double*)(wsb + B_WXE);
  double* WXD  = (double*)(wsb + B_WXD);
  double* Hd   = (double*)(wsb + B_H);
  float*  XT   = (float*)(wsb + B_XT);
  float*  DIN  = (float*)(wsb + B_DIN);
  int*    SY   = (int*)(wsb + B_SYNC);

  // Whh -> [r][k][uu][gate] in f64
  for (int i = idx; i < 1024*256; i += stride) {
    const int gate = i & 3, uu = (i >> 2) & 3, u = (i >> 4) & 255, rr = i >> 12;
    const int row = gate*256 + rr*4 + uu;
    WENC[i] = (double)eWhh[row*256 + u];
    WDEC[i] = (double)dWhh[row*256 + u];
  }
  // att_We / att_Wd -> [r][k][kk] in f64
  for (int i = idx; i < 256*256; i += stride) {
    const int kk = i & 3, u = (i >> 2) & 255, rr = i >> 10;
    const int row = rr*4 + kk;
    WEd[i] = (double)We[row*256 + u];
    WDd[i] = (double)Wd[row*256 + u];
  }
  // Wih + bias pack: [u][16] = {i0,i1,f0,f1,g0,g1,o0,o1, bi,bf,bg,bo, pad}
  for (int i = idx; i < 256*16; i += stride) {
    const int f = i & 15, u = i >> 4;
    double ve = 0.0, vd = 0.0;
    if (f < 8) {
      const int gg = f >> 1, d = f & 1;
      ve = (double)eWih[(gg*256+u)*2 + d];
      vd = (double)dWih[(gg*256+u)*2 + d];
    } else if (f < 12) {
      const int gg = f - 8;
      ve = (double)ebih[gg*256+u] + (double)ebhh[gg*256+u];
      vd = (double)dbih[gg*256+u] + (double)dbhh[gg*256+u];
    }
    WXE[i] = ve;
    WXD[i] = vd;
  }
  // x -> [t][b][d] (f32: exact values)
  for (int i = idx; i < 100*512*2; i += stride) {
    const int d = i & 1, b = (i >> 1) & 511, t = i >> 10;
    XT[i] = x[(b*100 + t)*2 + d];
  }
  for (int i = idx; i < 2*256*512; i += stride) Hd[i] = 0.0;
  for (int i = idx; i < 1024; i += stride) DIN[i] = start[i & 1];
  for (int i = idx; i < 1024; i += stride) SY[i] = 0;
}

extern "C" __global__ void __launch_bounds__(256, 2)
ptrnet_main(char* __restrict__ wsb,
            const float* __restrict__ att_be,
            const float* __restrict__ att_bd,
            const float* __restrict__ Vw,
            const float* __restrict__ Vb,
            float* __restrict__ out)
{
  __shared__ SMem sm;
  const int bid = blockIdx.x;
  const int g   = bid & 7;
  const int r   = bid >> 3;
  const int tid = threadIdx.x;
  const int lane = tid & 63;
  const int w = __builtin_amdgcn_readfirstlane(tid >> 6);
  const int bG = g * 64;
  const int myb = bG + r;

  double* hbuf = (double*)(wsb + B_H);
  float*  xT   = (float*)(wsb + B_XT);
  float*  din  = (float*)(wsb + B_DIN);
  double* dpw  = (double*)(wsb + B_DP);
  double* ep   = (double*)(wsb + B_EP);
  int* flags   = (int*)(wsb + B_SYNC);
  int* rel     = flags + 512;

  const double* Wg_e = (double*)(wsb + B_WENC) + r*(256*16);
  const double* Wg_d = (double*)(wsb + B_WDEC) + r*(256*16);
  const double* Weg  = (double*)(wsb + B_WE)   + r*(256*4);
  const double* Wdg  = (double*)(wsb + B_WD)   + r*(256*4);
  const double* WxbE = (double*)(wsb + B_WXE);
  const double* WxbD = (double*)(wsb + B_WXD);

  const double be_r = (double)att_be[4*r + (tid & 3)];
  const double bd_r = (double)att_bd[4*r + (tid & 3)];
  const double vb0  = (double)Vb[0];

  int epoch = 0;
  double c_state = 0.0;

  // ============================ encoder ============================
  for (int t = 0; t < 100; ++t) {
    const double* hsrc = hbuf + (t & 1) * 131072;
    double*       hdst = hbuf + ((t + 1) & 1) * 131072;
    double acc[4][4] = {};
    double epacc[4] = {0.0, 0.0, 0.0, 0.0};
    for (int jc = 0; jc < 4; ++jc) {
      const int u0 = w*64 + jc*16;
      double hreg[16];
      #pragma unroll
      for (int j = 0; j < 16; ++j)
        hreg[j] = ld_sys_d(&hsrc[(u0+j)*512 + bG + lane]);
      #pragma unroll
      for (int j = 0; j < 16; ++j) {
        const double hv = hreg[j];
        const double* wr = Wg_e + (u0+j)*16;   // cached, wave-uniform (s_load)
        #pragma unroll
        for (int q = 0; q < 4; ++q) {
          acc[q][0] = fma(wr[q*4+0], hv, acc[q][0]);
          acc[q][1] = fma(wr[q*4+1], hv, acc[q][1]);
          acc[q][2] = fma(wr[q*4+2], hv, acc[q][2]);
          acc[q][3] = fma(wr[q*4+3], hv, acc[q][3]);
        }
        const double* we = Weg + (u0+j)*4;
        epacc[0] = fma(we[0], hv, epacc[0]);
        epacc[1] = fma(we[1], hv, epacc[1]);
        epacc[2] = fma(we[2], hv, epacc[2]);
        epacc[3] = fma(we[3], hv, epacc[3]);
      }
    }
    #pragma unroll
    for (int q = 0; q < 4; ++q)
      #pragma unroll
      for (int gt = 0; gt < 4; ++gt)
        sm.gred[w][q][gt][lane] = acc[q][gt];
    #pragma unroll
    for (int k = 0; k < 4; ++k) sm.ered[w][k][lane] = epacc[k];
    __syncthreads();
    {
      double gi = sm.gred[0][w][0][lane] + sm.gred[1][w][0][lane] +
                  sm.gred[2][w][0][lane] + sm.gred[3][w][0][lane];
      double gf = sm.gred[0][w][1][lane] + sm.gred[1][w][1][lane] +
                  sm.gred[2][w][1][lane] + sm.gred[3][w][1][lane];
      double gg = sm.gred[0][w][2][lane] + sm.gred[1][w][2][lane] +
                  sm.gred[2][w][2][lane] + sm.gred[3][w][2][lane];
      double go = sm.gred[0][w][3][lane] + sm.gred[1][w][3][lane] +
                  sm.gred[2][w][3][lane] + sm.gred[3][w][3][lane];
      const double* wx = WxbE + (4*r + w)*16;
      const double x0 = (double)xT[t*1024 + (bG+lane)*2 + 0];
      const double x1 = (double)xT[t*1024 + (bG+lane)*2 + 1];
      gi += fma(wx[0], x0, fma(wx[1], x1, wx[8]));
      gf += fma(wx[2], x0, fma(wx[3], x1, wx[9]));
      gg += fma(wx[4], x0, fma(wx[5], x1, wx[10]));
      go += fma(wx[6], x0, fma(wx[7], x1, wx[11]));
      const double cn = sigmoid_d(gf)*c_state + sigmoid_d(gi)*tanh(gg);
      const double hn = sigmoid_d(go)*tanh(cn);
      c_state = cn;
      st_sys_d(&hdst[(4*r + w)*512 + bG + lane], hn);
    }
    if (t > 0) {  // ep[t-1] = We*h^(t) + be, f64 via system store
      const int b2 = tid >> 2, kk = tid & 3;
      const double e = sm.ered[0][kk][b2] + sm.ered[1][kk][b2] +
                       sm.ered[2][kk][b2] + sm.ered[3][kk][b2] + be_r;
      st_sys_d(&ep[(size_t)(bG + b2)*25600 + (t-1)*256 + 4*r + kk], e);
    }
    ++epoch; group_barrier(flags, rel, g, r, epoch);
  }

  // ep[99] tail on h^(100) (parity 0)
  {
    const double* hsrc = hbuf;
    double epacc[4] = {0.0, 0.0, 0.0, 0.0};
    for (int jc = 0; jc < 4; ++jc) {
      const int u0 = w*64 + jc*16;
      double hreg[16];
      #pragma unroll
      for (int j = 0; j < 16; ++j)
        hreg[j] = ld_sys_d(&hsrc[(u0+j)*512 + bG + lane]);
      #pragma unroll
      for (int j = 0; j < 16; ++j) {
        const double hv = hreg[j];
        const double* we = Weg + (u0+j)*4;
        epacc[0] = fma(we[0], hv, epacc[0]);
        epacc[1] = fma(we[1], hv, epacc[1]);
        epacc[2] = fma(we[2], hv, epacc[2]);
        epacc[3] = fma(we[3], hv, epacc[3]);
      }
    }
    #pragma unroll
    for (int k = 0; k < 4; ++k) sm.ered[w][k][lane] = epacc[k];
    __syncthreads();
    const int b2 = tid >> 2, kk = tid & 3;
    const double e = sm.ered[0][kk][b2] + sm.ered[1][kk][b2] +
                     sm.ered[2][kk][b2] + sm.ered[3][kk][b2] + be_r;
    st_sys_d(&ep[(size_t)(bG + b2)*25600 + 99*256 + 4*r + kk], e);
    ++epoch; group_barrier(flags, rel, g, r, epoch);
  }

  // ===================== decoder =====================
  const double vw_r = (double)Vw[tid];
  const double* myep = ep + (size_t)myb*25600 + tid;
  unsigned long long m0 = 0ull, m1 = 0ull;
  float lp_acc = 0.0f;

  for (int t = 0; t < 100; ++t) {
    const double* hsrc = hbuf + (t & 1) * 131072;
    double*       hdst = hbuf + ((t + 1) & 1) * 131072;
    // ---------- (a) decoder LSTM cell ----------
    {
      double acc[4][4] = {};
      for (int jc = 0; jc < 4; ++jc) {
        const int u0 = w*64 + jc*16;
        double hreg[16];
        #pragma unroll
        for (int j = 0; j < 16; ++j)
          hreg[j] = ld_sys_d(&hsrc[(u0+j)*512 + bG + lane]);
        #pragma unroll
        for (int j = 0; j < 16; ++j) {
          const double hv = hreg[j];
          const double* wr = Wg_d + (u0+j)*16;
          #pragma unroll
          for (int q = 0; q < 4; ++q) {
            acc[q][0] = fma(wr[q*4+0], hv, acc[q][0]);
            acc[q][1] = fma(wr[q*4+1], hv, acc[q][1]);
            acc[q][2] = fma(wr[q*4+2], hv, acc[q][2]);
            acc[q][3] = fma(wr[q*4+3], hv, acc[q][3]);
          }
        }
      }
      #pragma unroll
      for (int q = 0; q < 4; ++q)
        #pragma unroll
        for (int gt = 0; gt < 4; ++gt)
          sm.gred[w][q][gt][lane] = acc[q][gt];
      __syncthreads();
      double gi = sm.gred[0][w][0][lane] + sm.gred[1][w][0][lane] +
                  sm.gred[2][w][0][lane] + sm.gred[3][w][0][lane];
      double gf = sm.gred[0][w][1][lane] + sm.gred[1][w][1][lane] +
                  sm.gred[2][w][1][lane] + sm.gred[3][w][1][lane];
      double gg = sm.gred[0][w][2][lane] + sm.gred[1][w][2][lane] +
                  sm.gred[2][w][2][lane] + sm.gred[3][w][2][lane];
      double go = sm.gred[0][w][3][lane] + sm.gred[1][w][3][lane] +
                  sm.gred[2][w][3][lane] + sm.gred[3][w][3][lane];
      const double* wx = WxbD + (4*r + w)*16;
      const double x0 = (double)ld_sys_f(&din[(bG+lane)*2 + 0]);
      const double x1 = (double)ld_sys_f(&din[(bG+lane)*2 + 1]);
      gi += fma(wx[0], x0, fma(wx[1], x1, wx[8]));
      gf += fma(wx[2], x0, fma(wx[3], x1, wx[9]));
      gg += fma(wx[4], x0, fma(wx[5], x1, wx[10]));
      go += fma(wx[6], x0, fma(wx[7], x1, wx[11]));
      const double cn = sigmoid_d(gf)*c_state + sigmoid_d(gi)*tanh(gg);
      const double hn = sigmoid_d(go)*tanh(cn);
      c_state = cn;
      st_sys_d(&hdst[(4*r + w)*512 + bG + lane], hn);
    }
    ++epoch; group_barrier(flags, rel, g, r, epoch);
    // ---------- (b) dec_proj, f64 ----------
    {
      double dacc[4] = {0.0, 0.0, 0.0, 0.0};
      for (int jc = 0; jc < 4; ++jc) {
        const int u0 = w*64 + jc*16;
        double hreg[16];
        #pragma unroll
        for (int j = 0; j < 16; ++j)
          hreg[j] = ld_sys_d(&hdst[(u0+j)*512 + bG + lane]);
        #pragma unroll
        for (int j = 0; j < 16; ++j) {
          const double hv = hreg[j];
          const double* wr = Wdg + (u0+j)*4;
          dacc[0] = fma(wr[0], hv, dacc[0]);
          dacc[1] = fma(wr[1], hv, dacc[1]);
          dacc[2] = fma(wr[2], hv, dacc[2]);
          dacc[3] = fma(wr[3], hv, dacc[3]);
        }
      }
      #pragma unroll
      for (int k = 0; k < 4; ++k) sm.ered[w][k][lane] = dacc[k];
      __syncthreads();
      const int b2 = tid >> 2, kk = tid & 3;
      const double dv = sm.ered[0][kk][b2] + sm.ered[1][kk][b2] +
                        sm.ered[2][kk][b2] + sm.ered[3][kk][b2] + bd_r;
      st_sys_d(&dpw[(bG + b2)*256 + 4*r + kk], dv);
    }
    ++epoch; group_barrier(flags, rel, g, r, epoch);
    // ---------- (c) f64-exact scores -> np-faithful fp32 log_softmax ----------
    {
      const double dpl = ld_sys_d(&dpw[myb*256 + tid]);
      for (int s = 0; s < 100; ++s) {
        const bool masked = (s < 64) ? (((m0 >> s) & 1ull) != 0ull)
                                     : (((m1 >> (s-64)) & 1ull) != 0ull);
        if (!masked) {   // block-uniform -> whole-wave skip
          double p = tanh(ld_sys_d(&myep[s*256]) + dpl) * vw_r;
          p = wave64_sum_d(p);
          if (lane == 0) sm.sred[s][w] = p;
        }
      }
      __syncthreads();
      if (tid < 100) {
        const bool masked = (tid < 64) ? (((m0 >> tid) & 1ull) != 0ull)
                                       : (((m1 >> (tid-64)) & 1ull) != 0ull);
        // single rounding of the exact score to fp32 (reference dtype)
        sm.scores[tid] = masked ? -__builtin_inff()
                                : (float)(sm.sred[tid][0] + sm.sred[tid][1] +
                                          sm.sred[tid][2] + sm.sred[tid][3] + vb0);
      }
      __syncthreads();
      if (w == 0) {   // m = max(scores), fp32
        const float v0 = sm.scores[lane];
        const float v1 = (lane < 36) ? sm.scores[64 + lane] : -__builtin_inff();
        float mv = fmaxf(v0, v1);
        #pragma unroll
        for (int mm = 1; mm < 64; mm <<= 1)
          mv = fmaxf(mv, __shfl_xor(mv, mm, 64));
        if (lane == 0) sm.red_m = mv;
      }
      __syncthreads();
      if (tid < 100)
        sm.evals[tid] = expf(__fsub_rn(sm.scores[tid], sm.red_m));
      __syncthreads();
      if (tid == 0) {
        // numpy pairwise_sum for n=100: 8 accumulators over 0..95,
        // combine ((r0+r1)+(r2+r3))+((r4+r5)+(r6+r7)), sequential tail 96..99
        float rr[8];
        #pragma unroll
        for (int j = 0; j < 8; ++j) rr[j] = sm.evals[j];
        for (int i = 8; i < 96; i += 8) {
          #pragma unroll
          for (int j = 0; j < 8; ++j) rr[j] = __fadd_rn(rr[j], sm.evals[i + j]);
        }
        float res = __fadd_rn(
            __fadd_rn(__fadd_rn(rr[0], rr[1]), __fadd_rn(rr[2], rr[3])),
            __fadd_rn(__fadd_rn(rr[4], rr[5]), __fadd_rn(rr[6], rr[7])));
        res = __fadd_rn(res, sm.evals[96]);
        res = __fadd_rn(res, sm.evals[97]);
        res = __fadd_rn(res, sm.evals[98]);
        res = __fadd_rn(res, sm.evals[99]);
        sm.red_L = logf(res);
      }
      __syncthreads();
      if (w == 0) {   // lp = fl(fl(s - m) - L); argmax(lp), first index on ties
        const float m = sm.red_m, L = sm.red_L;
        const float lp0 = __fsub_rn(__fsub_rn(sm.scores[lane], m), L);
        const float lp1 = (lane < 36)
            ? __fsub_rn(__fsub_rn(sm.scores[64 + lane], m), L)
            : -__builtin_inff();
        float bv; int bi;
        if (lp0 >= lp1) { bv = lp0; bi = lane; } else { bv = lp1; bi = 64 + lane; }
        #pragma unroll
        for (int mm = 1; mm < 64; mm <<= 1) {
          const float ov = __shfl_xor(bv, mm, 64);
          const int   oi = __shfl_xor(bi, mm, 64);
          if (ov > bv || (ov == bv && oi < bi)) { bv = ov; bi = oi; }
        }
        if (lane == 0) { sm.bc_sel = bi; sm.bc_lp = bv; }
      }
      __syncthreads();
      const int sel = __builtin_amdgcn_readfirstlane(sm.bc_sel);
      lp_acc = __fadd_rn(lp_acc, sm.bc_lp);   // np axis-0 sum: sequential fp32
      if (sel < 64) m0 |= (1ull << sel); else m1 |= (1ull << (sel - 64));
      if (tid == 0) out[myb*100 + t] = (float)sel;
      if (tid < 2) st_sys_f(&din[myb*2 + tid], xT[sel*1024 + myb*2 + tid]);
    }
    ++epoch; group_barrier(flags, rel, g, r, epoch);
  }

  // ---------------- outputs ----------------
  if (tid == 0) out[51200 + myb] = lp_acc;
  out[51712 + myb*256 + tid] = (float)ld_sys_d(&hbuf[tid*512 + myb]);
}

extern "C" void kernel_launch(void* const* d_in, const int* in_sizes, int n_in,
                              void* d_out, int out_size, void* d_ws, size_t ws_size,
                              hipStream_t stream) {
  const float* x     = (const float*)d_in[0];
  const float* eWih  = (const float*)d_in[1];
  const float* eWhh  = (const float*)d_in[2];
  const float* ebih  = (const float*)d_in[3];
  const float* ebhh  = (const float*)d_in[4];
  const float* dWih  = (const float*)d_in[5];
  const float* dWhh  = (const float*)d_in[6];
  const float* dbih  = (const float*)d_in[7];
  const float* dbhh  = (const float*)d_in[8];
  const float* We    = (const float*)d_in[9];
  const float* be    = (const float*)d_in[10];
  const float* Wd    = (const float*)d_in[11];
  const float* bd    = (const float*)d_in[12];
  const float* vw    = (const float*)d_in[13];
  const float* vb    = (const float*)d_in[14];
  const float* start = (const float*)d_in[15];
  char* ws    = (char*)d_ws;
  float* outp = (float*)d_out;

  ptrnet_prep<<<dim3(512), dim3(256), 0, stream>>>(
      x, eWih, eWhh, ebih, ebhh, dWih, dWhh, dbih, dbhh, We, Wd, start, ws);

  ptrnet_main<<<dim3(512), dim3(256), 0, stream>>>(ws, be, bd, vw, vb, outp);
}

// Round 10
// 16108.133 us; speedup vs baseline: 1.7150x; 1.0822x over previous
//
#include <hip/hip_runtime.h>

// Pointer network: encoder LSTM -> enc_proj -> decoder LSTM + attention argmax.
// B=512, S=100, D=2, H=256.
//
// NUMERICS (FROZEN since R7, absmax 7.0 <= 7.2 -- do not touch):
//   TRAJECTORY = fp64 state evolution (h/c/gates/ep/dp f64, same orders).
//   SELECTION  = np-faithful fp32 log_softmax (pairwise-8 sum, lp quantization
//   tie-break to lower index), lp_acc sequential fp32.
//
// R10 change (structure only): XCD-LOCAL L2 communication.
//   Evidence: R7/R8 agent fences invalidated L2 -> 3.7GB weight refetch.
//   R9 system-scope data ops bypassed L2 -> 3.7GB uncached h stream at
//   ~240GB/s = the whole 17ms runtime (FETCH unchanged, VALU 27%).
//   Fix: group g = {bid%8==g} lands on XCD g (round-robin dispatch), so all
//   group traffic is intra-XCD and the per-XCD L2 is hardware-coherent for it.
//   Data (h/ep/dp/din) = AGENT-relaxed (sc0: L1-bypass, L2-cached, full BW,
//   no maintenance). Barrier flags = SYSTEM-relaxed single-writer stores +
//   system-relaxed polls (straight to L3, never cached -> barrier is correct
//   regardless of the XCD mapping; a wrong mapping shows as wrong data, not
//   deadlock). One s_waitcnt vmcnt(0) orders data stores before flag store.
//   ZERO cache-maintenance instructions in the whole kernel: weights stay
//   L2-resident across all ~400 phases.
//
// 512 blocks x 256 threads, plain launch; co-residency via
// __launch_bounds__(256,2) + ~45KB LDS -> exactly 2 blocks/CU x 256 CUs.
// group g = bid&7, role r = bid>>3; group owns batch [g*64, g*64+64).

#define B_WENC 0ull
#define B_WDEC (B_WENC + 1024ull*256ull*8ull)
#define B_WE   (B_WDEC + 1024ull*256ull*8ull)
#define B_WD   (B_WE   + 256ull*256ull*8ull)
#define B_WXE  (B_WD   + 256ull*256ull*8ull)
#define B_WXD  (B_WXE  + 256ull*16ull*8ull)
#define B_H    (B_WXD  + 256ull*16ull*8ull)
#define B_XT   (B_H    + 2ull*256ull*512ull*8ull)
#define B_DIN  (B_XT   + 100ull*512ull*2ull*4ull)
#define B_DP   (B_DIN  + 512ull*2ull*4ull)
#define B_EP   (B_DP   + 512ull*256ull*8ull)
#define B_SYNC (B_EP   + 512ull*100ull*256ull*8ull)

__device__ __forceinline__ double sigmoid_d(double x) {
  return 1.0 / (1.0 + exp(-x));
}

// ---- AGENT-relaxed accessors: sc0 only -- bypass L1, CACHED in the XCD-local
// ---- L2 (which is coherent for the group, since group == one XCD). No fences.
__device__ __forceinline__ double ld_a_d(const double* p) {
  return __hip_atomic_load((double*)p, __ATOMIC_RELAXED,
                           __HIP_MEMORY_SCOPE_AGENT);
}
__device__ __forceinline__ void st_a_d(double* p, double v) {
  __hip_atomic_store(p, v, __ATOMIC_RELAXED, __HIP_MEMORY_SCOPE_AGENT);
}
__device__ __forceinline__ float ld_a_f(const float* p) {
  return __hip_atomic_load((float*)p, __ATOMIC_RELAXED,
                           __HIP_MEMORY_SCOPE_AGENT);
}
__device__ __forceinline__ void st_a_f(float* p, float v) {
  __hip_atomic_store(p, v, __ATOMIC_RELAXED, __HIP_MEMORY_SCOPE_AGENT);
}
// ---- SYSTEM-relaxed flag accessors: sc0+sc1, straight to the coherence
// ---- point, never cached -> polls are always fresh on ANY XCD.
__device__ __forceinline__ int ld_s_i(const int* p) {
  return __hip_atomic_load((int*)p, __ATOMIC_RELAXED,
                           __HIP_MEMORY_SCOPE_SYSTEM);
}
__device__ __forceinline__ void st_s_i(int* p, int v) {
  __hip_atomic_store(p, v, __ATOMIC_RELAXED, __HIP_MEMORY_SCOPE_SYSTEM);
}

__device__ __forceinline__ double shfl_xor_d(double v, int m) {
  const long long l = __double_as_longlong(v);
  int lo = (int)(l & 0xffffffffll), hi = (int)(l >> 32);
  lo = __shfl_xor(lo, m, 64);
  hi = __shfl_xor(hi, m, 64);
  return __longlong_as_double(((long long)hi << 32) | (unsigned int)lo);
}

__device__ __forceinline__ double wave64_sum_d(double v) {
  #pragma unroll
  for (int m = 1; m < 64; m <<= 1) v += shfl_xor_d(v, m);
  return v;
}

// Group barrier, zero-cache-maintenance. Arrival: s_waitcnt vmcnt(0) (drain
// this block's sc0 data stores into L2) then single-writer SYSTEM store of the
// epoch into this role's slot. role-0 block gathers all 64 flags with one
// coalesced system load per iteration; releases via system store to rel slot.
// No fences, no invalidations, no RMWs.
__device__ __forceinline__ void group_barrier(int* flags, int* rel, int g, int r,
                                              int epoch) {
  __syncthreads();
  const int tid = threadIdx.x;
  if (tid == 0) {
    asm volatile("s_waitcnt vmcnt(0)" ::: "memory");  // data -> L2 before flag
    st_s_i(&flags[g*64 + r], epoch);
  }
  if (r == 0) {
    if (tid < 64) {
      for (;;) {
        const int v = ld_s_i(&flags[g*64 + tid]);
        if (__all(v >= epoch)) break;
        __builtin_amdgcn_s_sleep(2);
      }
      if (tid == 0) st_s_i(&rel[g*32], epoch);
    }
  } else if (tid == 0) {
    while (ld_s_i(&rel[g*32]) < epoch) __builtin_amdgcn_s_sleep(2);
  }
  __atomic_signal_fence(__ATOMIC_SEQ_CST);  // compiler-only ordering pin
  __syncthreads();
}

struct SMem {
  double gred[4][4][4][64];  // [writer wave][unit][gate][lane]  32 KB, 8B stride
  double ered[4][4][64];     // [writer wave][kk][lane]           8 KB
  double sred[100][4];       // per-s per-wave f64 partials      3.2 KB
  float  scores[104];
  float  evals[104];
  float  red_m, red_L;
  float  bc_lp;
  int    bc_sel;
};

extern "C" __global__ void ptrnet_prep(
    const float* __restrict__ x,
    const float* __restrict__ eWih, const float* __restrict__ eWhh,
    const float* __restrict__ ebih, const float* __restrict__ ebhh,
    const float* __restrict__ dWih, const float* __restrict__ dWhh,
    const float* __restrict__ dbih, const float* __restrict__ dbhh,
    const float* __restrict__ We,  const float* __restrict__ Wd,
    const float* __restrict__ start, char* __restrict__ wsb)
{
  const int idx = blockIdx.x * blockDim.x + threadIdx.x;
  const int stride = gridDim.x * blockDim.x;
  double* WENC = (double*)(wsb + B_WENC);
  double* WDEC = (double*)(wsb + B_WDEC);
  double* WEd  = (double*)(wsb + B_WE);
  double* WDd  = (double*)(wsb + B_WD);
  double* WXE  = (double*)(wsb + B_WXE);
  double* WXD  = (double*)(wsb + B_WXD);
  double* Hd   = (double*)(wsb + B_H);
  float*  XT   = (float*)(wsb + B_XT);
  float*  DIN  = (float*)(wsb + B_DIN);
  int*    SY   = (int*)(wsb + B_SYNC);

  // Whh -> [r][k][uu][gate] in f64
  for (int i = idx; i < 1024*256; i += stride) {
    const int gate = i & 3, uu = (i >> 2) & 3, u = (i >> 4) & 255, rr = i >> 12;
    const int row = gate*256 + rr*4 + uu;
    WENC[i] = (double)eWhh[row*256 + u];
    WDEC[i] = (double)dWhh[row*256 + u];
  }
  // att_We / att_Wd -> [r][k][kk] in f64
  for (int i = idx; i < 256*256; i += stride) {
    const int kk = i & 3, u = (i >> 2) & 255, rr = i >> 10;
    const int row = rr*4 + kk;
    WEd[i] = (double)We[row*256 + u];
    WDd[i] = (double)Wd[row*256 + u];
  }
  // Wih + bias pack: [u][16] = {i0,i1,f0,f1,g0,g1,o0,o1, bi,bf,bg,bo, pad}
  for (int i = idx; i < 256*16; i += stride) {
    const int f = i & 15, u = i >> 4;
    double ve = 0.0, vd = 0.0;
    if (f < 8) {
      const int gg = f >> 1, d = f & 1;
      ve = (double)eWih[(gg*256+u)*2 + d];
      vd = (double)dWih[(gg*256+u)*2 + d];
    } else if (f < 12) {
      const int gg = f - 8;
      ve = (double)ebih[gg*256+u] + (double)ebhh[gg*256+u];
      vd = (double)dbih[gg*256+u] + (double)dbhh[gg*256+u];
    }
    WXE[i] = ve;
    WXD[i] = vd;
  }
  // x -> [t][b][d] (f32: exact values)
  for (int i = idx; i < 100*512*2; i += stride) {
    const int d = i & 1, b = (i >> 1) & 511, t = i >> 10;
    XT[i] = x[(b*100 + t)*2 + d];
  }
  for (int i = idx; i < 2*256*512; i += stride) Hd[i] = 0.0;
  for (int i = idx; i < 1024; i += stride) DIN[i] = start[i & 1];
  for (int i = idx; i < 1024; i += stride) SY[i] = 0;
}

extern "C" __global__ void __launch_bounds__(256, 2)
ptrnet_main(char* __restrict__ wsb,
            const float* __restrict__ att_be,
            const float* __restrict__ att_bd,
            const float* __restrict__ Vw,
            const float* __restrict__ Vb,
            float* __restrict__ out)
{
  __shared__ SMem sm;
  const int bid = blockIdx.x;
  const int g   = bid & 7;
  const int r   = bid >> 3;
  const int tid = threadIdx.x;
  const int lane = tid & 63;
  const int w = __builtin_amdgcn_readfirstlane(tid >> 6);
  const int bG = g * 64;
  const int myb = bG + r;

  double* hbuf = (double*)(wsb + B_H);
  float*  xT   = (float*)(wsb + B_XT);
  float*  din  = (float*)(wsb + B_DIN);
  double* dpw  = (double*)(wsb + B_DP);
  double* ep   = (double*)(wsb + B_EP);
  int* flags   = (int*)(wsb + B_SYNC);
  int* rel     = flags + 512;

  const double* Wg_e = (double*)(wsb + B_WENC) + r*(256*16);
  const double* Wg_d = (double*)(wsb + B_WDEC) + r*(256*16);
  const double* Weg  = (double*)(wsb + B_WE)   + r*(256*4);
  const double* Wdg  = (double*)(wsb + B_WD)   + r*(256*4);
  const double* WxbE = (double*)(wsb + B_WXE);
  const double* WxbD = (double*)(wsb + B_WXD);

  const double be_r = (double)att_be[4*r + (tid & 3)];
  const double bd_r = (double)att_bd[4*r + (tid & 3)];
  const double vb0  = (double)Vb[0];

  int epoch = 0;
  double c_state = 0.0;

  // ============================ encoder ============================
  for (int t = 0; t < 100; ++t) {
    const double* hsrc = hbuf + (t & 1) * 131072;
    double*       hdst = hbuf + ((t + 1) & 1) * 131072;
    double acc[4][4] = {};
    double epacc[4] = {0.0, 0.0, 0.0, 0.0};
    for (int jc = 0; jc < 4; ++jc) {
      const int u0 = w*64 + jc*16;
      double hreg[16];
      #pragma unroll
      for (int j = 0; j < 16; ++j)
        hreg[j] = ld_a_d(&hsrc[(u0+j)*512 + bG + lane]);
      #pragma unroll
      for (int j = 0; j < 16; ++j) {
        const double hv = hreg[j];
        const double* wr = Wg_e + (u0+j)*16;   // cached, wave-uniform (s_load)
        #pragma unroll
        for (int q = 0; q < 4; ++q) {
          acc[q][0] = fma(wr[q*4+0], hv, acc[q][0]);
          acc[q][1] = fma(wr[q*4+1], hv, acc[q][1]);
          acc[q][2] = fma(wr[q*4+2], hv, acc[q][2]);
          acc[q][3] = fma(wr[q*4+3], hv, acc[q][3]);
        }
        const double* we = Weg + (u0+j)*4;
        epacc[0] = fma(we[0], hv, epacc[0]);
        epacc[1] = fma(we[1], hv, epacc[1]);
        epacc[2] = fma(we[2], hv, epacc[2]);
        epacc[3] = fma(we[3], hv, epacc[3]);
      }
    }
    #pragma unroll
    for (int q = 0; q < 4; ++q)
      #pragma unroll
      for (int gt = 0; gt < 4; ++gt)
        sm.gred[w][q][gt][lane] = acc[q][gt];
    #pragma unroll
    for (int k = 0; k < 4; ++k) sm.ered[w][k][lane] = epacc[k];
    __syncthreads();
    {
      double gi = sm.gred[0][w][0][lane] + sm.gred[1][w][0][lane] +
                  sm.gred[2][w][0][lane] + sm.gred[3][w][0][lane];
      double gf = sm.gred[0][w][1][lane] + sm.gred[1][w][1][lane] +
                  sm.gred[2][w][1][lane] + sm.gred[3][w][1][lane];
      double gg = sm.gred[0][w][2][lane] + sm.gred[1][w][2][lane] +
                  sm.gred[2][w][2][lane] + sm.gred[3][w][2][lane];
      double go = sm.gred[0][w][3][lane] + sm.gred[1][w][3][lane] +
                  sm.gred[2][w][3][lane] + sm.gred[3][w][3][lane];
      const double* wx = WxbE + (4*r + w)*16;
      const double x0 = (double)xT[t*1024 + (bG+lane)*2 + 0];
      const double x1 = (double)xT[t*1024 + (bG+lane)*2 + 1];
      gi += fma(wx[0], x0, fma(wx[1], x1, wx[8]));
      gf += fma(wx[2], x0, fma(wx[3], x1, wx[9]));
      gg += fma(wx[4], x0, fma(wx[5], x1, wx[10]));
      go += fma(wx[6], x0, fma(wx[7], x1, wx[11]));
      const double cn = sigmoid_d(gf)*c_state + sigmoid_d(gi)*tanh(gg);
      const double hn = sigmoid_d(go)*tanh(cn);
      c_state = cn;
      st_a_d(&hdst[(4*r + w)*512 + bG + lane], hn);
    }
    if (t > 0) {  // ep[t-1] = We*h^(t) + be, f64
      const int b2 = tid >> 2, kk = tid & 3;
      const double e = sm.ered[0][kk][b2] + sm.ered[1][kk][b2] +
                       sm.ered[2][kk][b2] + sm.ered[3][kk][b2] + be_r;
      st_a_d(&ep[(size_t)(bG + b2)*25600 + (t-1)*256 + 4*r + kk], e);
    }
    ++epoch; group_barrier(flags, rel, g, r, epoch);
  }

  // ep[99] tail on h^(100) (parity 0)
  {
    const double* hsrc = hbuf;
    double epacc[4] = {0.0, 0.0, 0.0, 0.0};
    for (int jc = 0; jc < 4; ++jc) {
      const int u0 = w*64 + jc*16;
      double hreg[16];
      #pragma unroll
      for (int j = 0; j < 16; ++j)
        hreg[j] = ld_a_d(&hsrc[(u0+j)*512 + bG + lane]);
      #pragma unroll
      for (int j = 0; j < 16; ++j) {
        const double hv = hreg[j];
        const double* we = Weg + (u0+j)*4;
        epacc[0] = fma(we[0], hv, epacc[0]);
        epacc[1] = fma(we[1], hv, epacc[1]);
        epacc[2] = fma(we[2], hv, epacc[2]);
        epacc[3] = fma(we[3], hv, epacc[3]);
      }
    }
    #pragma unroll
    for (int k = 0; k < 4; ++k) sm.ered[w][k][lane] = epacc[k];
    __syncthreads();
    const int b2 = tid >> 2, kk = tid & 3;
    const double e = sm.ered[0][kk][b2] + sm.ered[1][kk][b2] +
                     sm.ered[2][kk][b2] + sm.ered[3][kk][b2] + be_r;
    st_a_d(&ep[(size_t)(bG + b2)*25600 + 99*256 + 4*r + kk], e);
    ++epoch; group_barrier(flags, rel, g, r, epoch);
  }

  // ===================== decoder =====================
  const double vw_r = (double)Vw[tid];
  const double* myep = ep + (size_t)myb*25600 + tid;
  unsigned long long m0 = 0ull, m1 = 0ull;
  float lp_acc = 0.0f;

  for (int t = 0; t < 100; ++t) {
    const double* hsrc = hbuf + (t & 1) * 131072;
    double*       hdst = hbuf + ((t + 1) & 1) * 131072;
    // ---------- (a) decoder LSTM cell ----------
    {
      double acc[4][4] = {};
      for (int jc = 0; jc < 4; ++jc) {
        const int u0 = w*64 + jc*16;
        double hreg[16];
        #pragma unroll
        for (int j = 0; j < 16; ++j)
          hreg[j] = ld_a_d(&hsrc[(u0+j)*512 + bG + lane]);
        #pragma unroll
        for (int j = 0; j < 16; ++j) {
          const double hv = hreg[j];
          const double* wr = Wg_d + (u0+j)*16;
          #pragma unroll
          for (int q = 0; q < 4; ++q) {
            acc[q][0] = fma(wr[q*4+0], hv, acc[q][0]);
            acc[q][1] = fma(wr[q*4+1], hv, acc[q][1]);
            acc[q][2] = fma(wr[q*4+2], hv, acc[q][2]);
            acc[q][3] = fma(wr[q*4+3], hv, acc[q][3]);
          }
        }
      }
      #pragma unroll
      for (int q = 0; q < 4; ++q)
        #pragma unroll
        for (int gt = 0; gt < 4; ++gt)
          sm.gred[w][q][gt][lane] = acc[q][gt];
      __syncthreads();
      double gi = sm.gred[0][w][0][lane] + sm.gred[1][w][0][lane] +
                  sm.gred[2][w][0][lane] + sm.gred[3][w][0][lane];
      double gf = sm.gred[0][w][1][lane] + sm.gred[1][w][1][lane] +
                  sm.gred[2][w][1][lane] + sm.gred[3][w][1][lane];
      double gg = sm.gred[0][w][2][lane] + sm.gred[1][w][2][lane] +
                  sm.gred[2][w][2][lane] + sm.gred[3][w][2][lane];
      double go = sm.gred[0][w][3][lane] + sm.gred[1][w][3][lane] +
                  sm.gred[2][w][3][lane] + sm.gred[3][w][3][lane];
      const double* wx = WxbD + (4*r + w)*16;
      const double x0 = (double)ld_a_f(&din[(bG+lane)*2 + 0]);
      const double x1 = (double)ld_a_f(&din[(bG+lane)*2 + 1]);
      gi += fma(wx[0], x0, fma(wx[1], x1, wx[8]));
      gf += fma(wx[2], x0, fma(wx[3], x1, wx[9]));
      gg += fma(wx[4], x0, fma(wx[5], x1, wx[10]));
      go += fma(wx[6], x0, fma(wx[7], x1, wx[11]));
      const double cn = sigmoid_d(gf)*c_state + sigmoid_d(gi)*tanh(gg);
      const double hn = sigmoid_d(go)*tanh(cn);
      c_state = cn;
      st_a_d(&hdst[(4*r + w)*512 + bG + lane], hn);
    }
    ++epoch; group_barrier(flags, rel, g, r, epoch);
    // ---------- (b) dec_proj, f64 ----------
    {
      double dacc[4] = {0.0, 0.0, 0.0, 0.0};
      for (int jc = 0; jc < 4; ++jc) {
        const int u0 = w*64 + jc*16;
        double hreg[16];
        #pragma unroll
        for (int j = 0; j < 16; ++j)
          hreg[j] = ld_a_d(&hdst[(u0+j)*512 + bG + lane]);
        #pragma unroll
        for (int j = 0; j < 16; ++j) {
          const double hv = hreg[j];
          const double* wr = Wdg + (u0+j)*4;
          dacc[0] = fma(wr[0], hv, dacc[0]);
          dacc[1] = fma(wr[1], hv, dacc[1]);
          dacc[2] = fma(wr[2], hv, dacc[2]);
          dacc[3] = fma(wr[3], hv, dacc[3]);
        }
      }
      #pragma unroll
      for (int k = 0; k < 4; ++k) sm.ered[w][k][lane] = dacc[k];
      __syncthreads();
      const int b2 = tid >> 2, kk = tid & 3;
      const double dv = sm.ered[0][kk][b2] + sm.ered[1][kk][b2] +
                        sm.ered[2][kk][b2] + sm.ered[3][kk][b2] + bd_r;
      st_a_d(&dpw[(bG + b2)*256 + 4*r + kk], dv);
    }
    ++epoch; group_barrier(flags, rel, g, r, epoch);
    // ---------- (c) f64-exact scores -> np-faithful fp32 log_softmax ----------
    {
      const double dpl = ld_a_d(&dpw[myb*256 + tid]);
      for (int s = 0; s < 100; ++s) {
        const bool masked = (s < 64) ? (((m0 >> s) & 1ull) != 0ull)
                                     : (((m1 >> (s-64)) & 1ull) != 0ull);
        if (!masked) {   // block-uniform -> whole-wave skip
          double p = tanh(ld_a_d(&myep[s*256]) + dpl) * vw_r;
          p = wave64_sum_d(p);
          if (lane == 0) sm.sred[s][w] = p;
        }
      }
      __syncthreads();
      if (tid < 100) {
        const bool masked = (tid < 64) ? (((m0 >> tid) & 1ull) != 0ull)
                                       : (((m1 >> (tid-64)) & 1ull) != 0ull);
        // single rounding of the exact score to fp32 (reference dtype)
        sm.scores[tid] = masked ? -__builtin_inff()
                                : (float)(sm.sred[tid][0] + sm.sred[tid][1] +
                                          sm.sred[tid][2] + sm.sred[tid][3] + vb0);
      }
      __syncthreads();
      if (w == 0) {   // m = max(scores), fp32
        const float v0 = sm.scores[lane];
        const float v1 = (lane < 36) ? sm.scores[64 + lane] : -__builtin_inff();
        float mv = fmaxf(v0, v1);
        #pragma unroll
        for (int mm = 1; mm < 64; mm <<= 1)
          mv = fmaxf(mv, __shfl_xor(mv, mm, 64));
        if (lane == 0) sm.red_m = mv;
      }
      __syncthreads();
      if (tid < 100)
        sm.evals[tid] = expf(__fsub_rn(sm.scores[tid], sm.red_m));
      __syncthreads();
      if (tid == 0) {
        // numpy pairwise_sum for n=100: 8 accumulators over 0..95,
        // combine ((r0+r1)+(r2+r3))+((r4+r5)+(r6+r7)), sequential tail 96..99
        float rr[8];
        #pragma unroll
        for (int j = 0; j < 8; ++j) rr[j] = sm.evals[j];
        for (int i = 8; i < 96; i += 8) {
          #pragma unroll
          for (int j = 0; j < 8; ++j) rr[j] = __fadd_rn(rr[j], sm.evals[i + j]);
        }
        float res = __fadd_rn(
            __fadd_rn(__fadd_rn(rr[0], rr[1]), __fadd_rn(rr[2], rr[3])),
            __fadd_rn(__fadd_rn(rr[4], rr[5]), __fadd_rn(rr[6], rr[7])));
        res = __fadd_rn(res, sm.evals[96]);
        res = __fadd_rn(res, sm.evals[97]);
        res = __fadd_rn(res, sm.evals[98]);
        res = __fadd_rn(res, sm.evals[99]);
        sm.red_L = logf(res);
      }
      __syncthreads();
      if (w == 0) {   // lp = fl(fl(s - m) - L); argmax(lp), first index on ties
        const float m = sm.red_m, L = sm.red_L;
        const float lp0 = __fsub_rn(__fsub_rn(sm.scores[lane], m), L);
        const float lp1 = (lane < 36)
            ? __fsub_rn(__fsub_rn(sm.scores[64 + lane], m), L)
            : -__builtin_inff();
        float bv; int bi;
        if (lp0 >= lp1) { bv = lp0; bi = lane; } else { bv = lp1; bi = 64 + lane; }
        #pragma unroll
        for (int mm = 1; mm < 64; mm <<= 1) {
          const float ov = __shfl_xor(bv, mm, 64);
          const int   oi = __shfl_xor(bi, mm, 64);
          if (ov > bv || (ov == bv && oi < bi)) { bv = ov; bi = oi; }
        }
        if (lane == 0) { sm.bc_sel = bi; sm.bc_lp = bv; }
      }
      __syncthreads();
      const int sel = __builtin_amdgcn_readfirstlane(sm.bc_sel);
      lp_acc = __fadd_rn(lp_acc, sm.bc_lp);   // np axis-0 sum: sequential fp32
      if (sel < 64) m0 |= (1ull << sel); else m1 |= (1ull << (sel - 64));
      if (tid == 0) out[myb*100 + t] = (float)sel;
      if (tid < 2) st_a_f(&din[myb*2 + tid], xT[sel*1024 + myb*2 + tid]);
    }
    ++epoch; group_barrier(flags, rel, g, r, epoch);
  }

  // ---------------- outputs ----------------
  if (tid == 0) out[51200 + myb] = lp_acc;
  out[51712 + myb*256 + tid] = (float)ld_a_d(&hbuf[tid*512 + myb]);
}

extern "C" void kernel_launch(void* const* d_in, const int* in_sizes, int n_in,
                              void* d_out, int out_size, void* d_ws, size_t ws_size,
                              hipStream_t stream) {
  const float* x     = (const float*)d_in[0];
  const float* eWih  = (const float*)d_in[1];
  const float* eWhh  = (const float*)d_in[2];
  const float* ebih  = (const float*)d_in[3];
  const float* ebhh  = (const float*)d_in[4];
  const float* dWih  = (const float*)d_in[5];
  const float* dWhh  = (const float*)d_in[6];
  const float* dbih  = (const float*)d_in[7];
  const float* dbhh  = (const float*)d_in[8];
  const float* We    = (const float*)d_in[9];
  const float* be    = (const float*)d_in[10];
  const float* Wd    = (const float*)d_in[11];
  const float* bd    = (const float*)d_in[12];
  const float* vw    = (const float*)d_in[13];
  const float* vb    = (const float*)d_in[14];
  const float* start = (const float*)d_in[15];
  char* ws    = (char*)d_ws;
  float* outp = (float*)d_out;

  ptrnet_prep<<<dim3(512), dim3(256), 0, stream>>>(
      x, eWih, eWhh, ebih, ebhh, dWih, dWhh, dbih, dbhh, We, Wd, start, ws);

  ptrnet_main<<<dim3(512), dim3(256), 0, stream>>>(ws, be, bd, vw, vb, outp);
}

// Round 11
// 15847.670 us; speedup vs baseline: 1.7432x; 1.0164x over previous
//
#include <hip/hip_runtime.h>

// Pointer network: encoder LSTM -> enc_proj -> decoder LSTM + attention argmax.
// B=512, S=100, D=2, H=256.
//
// NUMERICS (FROZEN since R7, absmax 7.0 <= 7.2): f64 trajectory (any f64 order;
// error ~1e-13 << decision gaps) + EXACT np-faithful fp32 log_softmax selection
// (single f32 rounding of scores, pairwise-8 sum of exps, lp=fl(fl(s-m)-L),
// argmax(lp) first-index, lp_acc sequential fp32). Do not touch selection.
//
// R11 change (data-path routing only). Evidence: R9 vs R10 FETCH identical
// (3.71GB) -> HIP agent-scope atomics compile to L2-BYPASSING memory-side ops
// on gfx950 (agent coherence point is past the non-coherent per-XCD L2s).
// Traffic audit: h re-reads 2.4GB + decoder ep stream 1.3GB on that ~260GB/s
// path = the 16ms runtime (VALU floor 4.8ms).
// Routing now:
//  - ep: IMMUTABLE after encoder -> plain nontemporal loads (never stale: no
//    cached copy can exist before first read, never modified after). nt keeps
//    the stream from evicting weights.
//  - h/dpw/din: mutable, group-local -> inline-asm sc0 loads/stores (L1 bypass,
//    L2 CACHED). Correct iff group g = bid%8 lands on XCD g (round-robin
//    dispatch) so the XCD-local L2 is coherent for the group. If this mapping
//    assumption is wrong the bench fails loudly -> revert.
//  - weights/xT: plain cached (L2-resident, zero fences in kernel).
//  - barrier: system-scope flag stores/polls (mapping-independent, proven).
//
// 512 blocks x 256 threads; co-residency via __launch_bounds__(256,2).
// group g = bid&7, role r = bid>>3; group owns batch [g*64, g*64+64).

#define B_WENC 0ull
#define B_WDEC (B_WENC + 1024ull*256ull*8ull)
#define B_WE   (B_WDEC + 1024ull*256ull*8ull)
#define B_WD   (B_WE   + 256ull*256ull*8ull)
#define B_WXE  (B_WD   + 256ull*256ull*8ull)
#define B_WXD  (B_WXE  + 256ull*16ull*8ull)
#define B_H    (B_WXD  + 256ull*16ull*8ull)
#define B_XT   (B_H    + 2ull*256ull*512ull*8ull)
#define B_DIN  (B_XT   + 100ull*512ull*2ull*4ull)
#define B_DP   (B_DIN  + 512ull*2ull*4ull)
#define B_EP   (B_DP   + 512ull*256ull*8ull)
#define B_SYNC (B_EP   + 512ull*100ull*256ull*8ull)

__device__ __forceinline__ double sigmoid_d(double x) {
  return 1.0 / (1.0 + exp(-x));
}

// ---- sc0 (L1-bypass, L2-cached) accessors for XCD-local mutable data ----
__device__ __forceinline__ double ld1_l2_d(const double* p) {
  double r;
  asm volatile("global_load_dwordx2 %0, %1, off sc0\n\t"
               "s_waitcnt vmcnt(0)"
               : "=&v"(r) : "v"(p) : "memory");
  return r;
}
__device__ __forceinline__ float ld1_l2_f(const float* p) {
  float r;
  asm volatile("global_load_dword %0, %1, off sc0\n\t"
               "s_waitcnt vmcnt(0)"
               : "=&v"(r) : "v"(p) : "memory");
  return r;
}
__device__ __forceinline__ void ld4_l2_d(const double* p0, const double* p1,
                                         const double* p2, const double* p3,
                                         double& r0, double& r1,
                                         double& r2, double& r3) {
  asm volatile("global_load_dwordx2 %0, %4, off sc0\n\t"
               "global_load_dwordx2 %1, %5, off sc0\n\t"
               "global_load_dwordx2 %2, %6, off sc0\n\t"
               "global_load_dwordx2 %3, %7, off sc0\n\t"
               "s_waitcnt vmcnt(0)"
               : "=&v"(r0), "=&v"(r1), "=&v"(r2), "=&v"(r3)
               : "v"(p0), "v"(p1), "v"(p2), "v"(p3)
               : "memory");
}
__device__ __forceinline__ void st_l2_d(double* p, double v) {
  asm volatile("global_store_dwordx2 %0, %1, off sc0"
               :: "v"(p), "v"(v) : "memory");
}
__device__ __forceinline__ void st_l2_f(float* p, float v) {
  asm volatile("global_store_dword %0, %1, off sc0"
               :: "v"(p), "v"(v) : "memory");
}
// ---- SYSTEM-relaxed flag accessors (memory-side, mapping-independent) ----
__device__ __forceinline__ int ld_s_i(const int* p) {
  return __hip_atomic_load((int*)p, __ATOMIC_RELAXED,
                           __HIP_MEMORY_SCOPE_SYSTEM);
}
__device__ __forceinline__ void st_s_i(int* p, int v) {
  __hip_atomic_store(p, v, __ATOMIC_RELAXED, __HIP_MEMORY_SCOPE_SYSTEM);
}

__device__ __forceinline__ double shfl_xor_d(double v, int m) {
  const long long l = __double_as_longlong(v);
  int lo = (int)(l & 0xffffffffll), hi = (int)(l >> 32);
  lo = __shfl_xor(lo, m, 64);
  hi = __shfl_xor(hi, m, 64);
  return __longlong_as_double(((long long)hi << 32) | (unsigned int)lo);
}

__device__ __forceinline__ double wave64_sum_d(double v) {
  #pragma unroll
  for (int m = 1; m < 64; m <<= 1) v += shfl_xor_d(v, m);
  return v;
}

// Group barrier. __syncthreads() drains each wave's vmem (compiler emits
// vmcnt(0) before s_barrier) -> all sc0 stores are in L2 before tid0 posts the
// system-scope flag. Polls are system-relaxed (always fresh, no maintenance).
__device__ __forceinline__ void group_barrier(int* flags, int* rel, int g, int r,
                                              int epoch) {
  __syncthreads();
  const int tid = threadIdx.x;
  if (tid == 0) {
    asm volatile("s_waitcnt vmcnt(0)" ::: "memory");
    st_s_i(&flags[g*64 + r], epoch);
  }
  if (r == 0) {
    if (tid < 64) {
      for (;;) {
        const int v = ld_s_i(&flags[g*64 + tid]);
        if (__all(v >= epoch)) break;
        __builtin_amdgcn_s_sleep(2);
      }
      if (tid == 0) st_s_i(&rel[g*32], epoch);
    }
  } else if (tid == 0) {
    while (ld_s_i(&rel[g*32]) < epoch) __builtin_amdgcn_s_sleep(2);
  }
  __atomic_signal_fence(__ATOMIC_SEQ_CST);  // compiler-only ordering pin
  __syncthreads();
}

struct SMem {
  double gred[4][4][4][64];  // [writer wave][unit][gate][lane]  32 KB
  double ered[4][4][64];     // [writer wave][kk][lane]           8 KB
  double sred[100][4];
  float  scores[104];
  float  evals[104];
  float  red_m, red_L;
  float  bc_lp;
  int    bc_sel;
};

extern "C" __global__ void ptrnet_prep(
    const float* __restrict__ x,
    const float* __restrict__ eWih, const float* __restrict__ eWhh,
    const float* __restrict__ ebih, const float* __restrict__ ebhh,
    const float* __restrict__ dWih, const float* __restrict__ dWhh,
    const float* __restrict__ dbih, const float* __restrict__ dbhh,
    const float* __restrict__ We,  const float* __restrict__ Wd,
    const float* __restrict__ start, char* __restrict__ wsb)
{
  const int idx = blockIdx.x * blockDim.x + threadIdx.x;
  const int stride = gridDim.x * blockDim.x;
  double* WENC = (double*)(wsb + B_WENC);
  double* WDEC = (double*)(wsb + B_WDEC);
  double* WEd  = (double*)(wsb + B_WE);
  double* WDd  = (double*)(wsb + B_WD);
  double* WXE  = (double*)(wsb + B_WXE);
  double* WXD  = (double*)(wsb + B_WXD);
  double* Hd   = (double*)(wsb + B_H);
  float*  XT   = (float*)(wsb + B_XT);
  float*  DIN  = (float*)(wsb + B_DIN);
  int*    SY   = (int*)(wsb + B_SYNC);

  // Whh -> [r][k][uu][gate] in f64
  for (int i = idx; i < 1024*256; i += stride) {
    const int gate = i & 3, uu = (i >> 2) & 3, u = (i >> 4) & 255, rr = i >> 12;
    const int row = gate*256 + rr*4 + uu;
    WENC[i] = (double)eWhh[row*256 + u];
    WDEC[i] = (double)dWhh[row*256 + u];
  }
  // att_We / att_Wd -> [r][k][kk] in f64
  for (int i = idx; i < 256*256; i += stride) {
    const int kk = i & 3, u = (i >> 2) & 255, rr = i >> 10;
    const int row = rr*4 + kk;
    WEd[i] = (double)We[row*256 + u];
    WDd[i] = (double)Wd[row*256 + u];
  }
  // Wih + bias pack: [u][16] = {i0,i1,f0,f1,g0,g1,o0,o1, bi,bf,bg,bo, pad}
  for (int i = idx; i < 256*16; i += stride) {
    const int f = i & 15, u = i >> 4;
    double ve = 0.0, vd = 0.0;
    if (f < 8) {
      const int gg = f >> 1, d = f & 1;
      ve = (double)eWih[(gg*256+u)*2 + d];
      vd = (double)dWih[(gg*256+u)*2 + d];
    } else if (f < 12) {
      const int gg = f - 8;
      ve = (double)ebih[gg*256+u] + (double)ebhh[gg*256+u];
      vd = (double)dbih[gg*256+u] + (double)dbhh[gg*256+u];
    }
    WXE[i] = ve;
    WXD[i] = vd;
  }
  // x -> [t][b][d] (f32: exact values)
  for (int i = idx; i < 100*512*2; i += stride) {
    const int d = i & 1, b = (i >> 1) & 511, t = i >> 10;
    XT[i] = x[(b*100 + t)*2 + d];
  }
  for (int i = idx; i < 2*256*512; i += stride) Hd[i] = 0.0;
  for (int i = idx; i < 1024; i += stride) DIN[i] = start[i & 1];
  for (int i = idx; i < 1024; i += stride) SY[i] = 0;
}

extern "C" __global__ void __launch_bounds__(256, 2)
ptrnet_main(char* __restrict__ wsb,
            const float* __restrict__ att_be,
            const float* __restrict__ att_bd,
            const float* __restrict__ Vw,
            const float* __restrict__ Vb,
            float* __restrict__ out)
{
  __shared__ SMem sm;
  const int bid = blockIdx.x;
  const int g   = bid & 7;
  const int r   = bid >> 3;
  const int tid = threadIdx.x;
  const int lane = tid & 63;
  const int w = __builtin_amdgcn_readfirstlane(tid >> 6);
  const int bG = g * 64;
  const int myb = bG + r;

  double* hbuf = (double*)(wsb + B_H);
  float*  xT   = (float*)(wsb + B_XT);
  float*  din  = (float*)(wsb + B_DIN);
  double* dpw  = (double*)(wsb + B_DP);
  double* ep   = (double*)(wsb + B_EP);
  int* flags   = (int*)(wsb + B_SYNC);
  int* rel     = flags + 512;

  const double* Wg_e = (double*)(wsb + B_WENC) + r*(256*16);
  const double* Wg_d = (double*)(wsb + B_WDEC) + r*(256*16);
  const double* Weg  = (double*)(wsb + B_WE)   + r*(256*4);
  const double* Wdg  = (double*)(wsb + B_WD)   + r*(256*4);
  const double* WxbE = (double*)(wsb + B_WXE);
  const double* WxbD = (double*)(wsb + B_WXD);

  const double be_r = (double)att_be[4*r + (tid & 3)];
  const double bd_r = (double)att_bd[4*r + (tid & 3)];
  const double vb0  = (double)Vb[0];

  int epoch = 0;
  double c_state = 0.0;

  // ============================ encoder ============================
  for (int t = 0; t < 100; ++t) {
    const double* hsrc = hbuf + (t & 1) * 131072;
    double*       hdst = hbuf + ((t + 1) & 1) * 131072;
    double acc[4][4] = {};
    double epacc[4] = {0.0, 0.0, 0.0, 0.0};
    for (int jc = 0; jc < 4; ++jc) {
      const int u0 = w*64 + jc*16;
      const int off = bG + lane;
      double hreg[16];
      #pragma unroll
      for (int jq = 0; jq < 4; ++jq)
        ld4_l2_d(&hsrc[(u0+jq*4+0)*512 + off], &hsrc[(u0+jq*4+1)*512 + off],
                 &hsrc[(u0+jq*4+2)*512 + off], &hsrc[(u0+jq*4+3)*512 + off],
                 hreg[jq*4+0], hreg[jq*4+1], hreg[jq*4+2], hreg[jq*4+3]);
      #pragma unroll
      for (int j = 0; j < 16; ++j) {
        const double hv = hreg[j];
        const double* wr = Wg_e + (u0+j)*16;   // cached, wave-uniform (s_load)
        #pragma unroll
        for (int q = 0; q < 4; ++q) {
          acc[q][0] = fma(wr[q*4+0], hv, acc[q][0]);
          acc[q][1] = fma(wr[q*4+1], hv, acc[q][1]);
          acc[q][2] = fma(wr[q*4+2], hv, acc[q][2]);
          acc[q][3] = fma(wr[q*4+3], hv, acc[q][3]);
        }
        const double* we = Weg + (u0+j)*4;
        epacc[0] = fma(we[0], hv, epacc[0]);
        epacc[1] = fma(we[1], hv, epacc[1]);
        epacc[2] = fma(we[2], hv, epacc[2]);
        epacc[3] = fma(we[3], hv, epacc[3]);
      }
    }
    #pragma unroll
    for (int q = 0; q < 4; ++q)
      #pragma unroll
      for (int gt = 0; gt < 4; ++gt)
        sm.gred[w][q][gt][lane] = acc[q][gt];
    #pragma unroll
    for (int k = 0; k < 4; ++k) sm.ered[w][k][lane] = epacc[k];
    __syncthreads();
    {
      double gi = sm.gred[0][w][0][lane] + sm.gred[1][w][0][lane] +
                  sm.gred[2][w][0][lane] + sm.gred[3][w][0][lane];
      double gf = sm.gred[0][w][1][lane] + sm.gred[1][w][1][lane] +
                  sm.gred[2][w][1][lane] + sm.gred[3][w][1][lane];
      double gg = sm.gred[0][w][2][lane] + sm.gred[1][w][2][lane] +
                  sm.gred[2][w][2][lane] + sm.gred[3][w][2][lane];
      double go = sm.gred[0][w][3][lane] + sm.gred[1][w][3][lane] +
                  sm.gred[2][w][3][lane] + sm.gred[3][w][3][lane];
      const double* wx = WxbE + (4*r + w)*16;
      const double x0 = (double)xT[t*1024 + (bG+lane)*2 + 0];
      const double x1 = (double)xT[t*1024 + (bG+lane)*2 + 1];
      gi += fma(wx[0], x0, fma(wx[1], x1, wx[8]));
      gf += fma(wx[2], x0, fma(wx[3], x1, wx[9]));
      gg += fma(wx[4], x0, fma(wx[5], x1, wx[10]));
      go += fma(wx[6], x0, fma(wx[7], x1, wx[11]));
      const double cn = sigmoid_d(gf)*c_state + sigmoid_d(gi)*tanh(gg);
      const double hn = sigmoid_d(go)*tanh(cn);
      c_state = cn;
      st_l2_d(&hdst[(4*r + w)*512 + bG + lane], hn);
    }
    if (t > 0) {  // ep[t-1] = We*h^(t) + be, f64 (sc0 -> XCD L2)
      const int b2 = tid >> 2, kk = tid & 3;
      const double e = sm.ered[0][kk][b2] + sm.ered[1][kk][b2] +
                       sm.ered[2][kk][b2] + sm.ered[3][kk][b2] + be_r;
      st_l2_d(&ep[(size_t)(bG + b2)*25600 + (t-1)*256 + 4*r + kk], e);
    }
    ++epoch; group_barrier(flags, rel, g, r, epoch);
  }

  // ep[99] tail on h^(100) (parity 0)
  {
    const double* hsrc = hbuf;
    const int off = bG + lane;
    double epacc[4] = {0.0, 0.0, 0.0, 0.0};
    for (int jc = 0; jc < 4; ++jc) {
      const int u0 = w*64 + jc*16;
      double hreg[16];
      #pragma unroll
      for (int jq = 0; jq < 4; ++jq)
        ld4_l2_d(&hsrc[(u0+jq*4+0)*512 + off], &hsrc[(u0+jq*4+1)*512 + off],
                 &hsrc[(u0+jq*4+2)*512 + off], &hsrc[(u0+jq*4+3)*512 + off],
                 hreg[jq*4+0], hreg[jq*4+1], hreg[jq*4+2], hreg[jq*4+3]);
      #pragma unroll
      for (int j = 0; j < 16; ++j) {
        const double hv = hreg[j];
        const double* we = Weg + (u0+j)*4;
        epacc[0] = fma(we[0], hv, epacc[0]);
        epacc[1] = fma(we[1], hv, epacc[1]);
        epacc[2] = fma(we[2], hv, epacc[2]);
        epacc[3] = fma(we[3], hv, epacc[3]);
      }
    }
    #pragma unroll
    for (int k = 0; k < 4; ++k) sm.ered[w][k][lane] = epacc[k];
    __syncthreads();
    const int b2 = tid >> 2, kk = tid & 3;
    const double e = sm.ered[0][kk][b2] + sm.ered[1][kk][b2] +
                     sm.ered[2][kk][b2] + sm.ered[3][kk][b2] + be_r;
    st_l2_d(&ep[(size_t)(bG + b2)*25600 + 99*256 + 4*r + kk], e);
    ++epoch; group_barrier(flags, rel, g, r, epoch);
  }

  // ===================== decoder =====================
  const double vw_r = (double)Vw[tid];
  const double* myep = ep + (size_t)myb*25600 + tid;
  unsigned long long m0 = 0ull, m1 = 0ull;
  float lp_acc = 0.0f;

  for (int t = 0; t < 100; ++t) {
    const double* hsrc = hbuf + (t & 1) * 131072;
    double*       hdst = hbuf + ((t + 1) & 1) * 131072;
    // ---------- (a) decoder LSTM cell ----------
    {
      const int off = bG + lane;
      double acc[4][4] = {};
      for (int jc = 0; jc < 4; ++jc) {
        const int u0 = w*64 + jc*16;
        double hreg[16];
        #pragma unroll
        for (int jq = 0; jq < 4; ++jq)
          ld4_l2_d(&hsrc[(u0+jq*4+0)*512 + off], &hsrc[(u0+jq*4+1)*512 + off],
                   &hsrc[(u0+jq*4+2)*512 + off], &hsrc[(u0+jq*4+3)*512 + off],
                   hreg[jq*4+0], hreg[jq*4+1], hreg[jq*4+2], hreg[jq*4+3]);
        #pragma unroll
        for (int j = 0; j < 16; ++j) {
          const double hv = hreg[j];
          const double* wr = Wg_d + (u0+j)*16;
          #pragma unroll
          for (int q = 0; q < 4; ++q) {
            acc[q][0] = fma(wr[q*4+0], hv, acc[q][0]);
            acc[q][1] = fma(wr[q*4+1], hv, acc[q][1]);
            acc[q][2] = fma(wr[q*4+2], hv, acc[q][2]);
            acc[q][3] = fma(wr[q*4+3], hv, acc[q][3]);
          }
        }
      }
      #pragma unroll
      for (int q = 0; q < 4; ++q)
        #pragma unroll
        for (int gt = 0; gt < 4; ++gt)
          sm.gred[w][q][gt][lane] = acc[q][gt];
      __syncthreads();
      double gi = sm.gred[0][w][0][lane] + sm.gred[1][w][0][lane] +
                  sm.gred[2][w][0][lane] + sm.gred[3][w][0][lane];
      double gf = sm.gred[0][w][1][lane] + sm.gred[1][w][1][lane] +
                  sm.gred[2][w][1][lane] + sm.gred[3][w][1][lane];
      double gg = sm.gred[0][w][2][lane] + sm.gred[1][w][2][lane] +
                  sm.gred[2][w][2][lane] + sm.gred[3][w][2][lane];
      double go = sm.gred[0][w][3][lane] + sm.gred[1][w][3][lane] +
                  sm.gred[2][w][3][lane] + sm.gred[3][w][3][lane];
      const double* wx = WxbD + (4*r + w)*16;
      const double x0 = (double)ld1_l2_f(&din[(bG+lane)*2 + 0]);
      const double x1 = (double)ld1_l2_f(&din[(bG+lane)*2 + 1]);
      gi += fma(wx[0], x0, fma(wx[1], x1, wx[8]));
      gf += fma(wx[2], x0, fma(wx[3], x1, wx[9]));
      gg += fma(wx[4], x0, fma(wx[5], x1, wx[10]));
      go += fma(wx[6], x0, fma(wx[7], x1, wx[11]));
      const double cn = sigmoid_d(gf)*c_state + sigmoid_d(gi)*tanh(gg);
      const double hn = sigmoid_d(go)*tanh(cn);
      c_state = cn;
      st_l2_d(&hdst[(4*r + w)*512 + bG + lane], hn);
    }
    ++epoch; group_barrier(flags, rel, g, r, epoch);
    // ---------- (b) dec_proj, f64 ----------
    {
      const int off = bG + lane;
      double dacc[4] = {0.0, 0.0, 0.0, 0.0};
      for (int jc = 0; jc < 4; ++jc) {
        const int u0 = w*64 + jc*16;
        double hreg[16];
        #pragma unroll
        for (int jq = 0; jq < 4; ++jq)
          ld4_l2_d(&hdst[(u0+jq*4+0)*512 + off], &hdst[(u0+jq*4+1)*512 + off],
                   &hdst[(u0+jq*4+2)*512 + off], &hdst[(u0+jq*4+3)*512 + off],
                   hreg[jq*4+0], hreg[jq*4+1], hreg[jq*4+2], hreg[jq*4+3]);
        #pragma unroll
        for (int j = 0; j < 16; ++j) {
          const double hv = hreg[j];
          const double* wr = Wdg + (u0+j)*4;
          dacc[0] = fma(wr[0], hv, dacc[0]);
          dacc[1] = fma(wr[1], hv, dacc[1]);
          dacc[2] = fma(wr[2], hv, dacc[2]);
          dacc[3] = fma(wr[3], hv, dacc[3]);
        }
      }
      #pragma unroll
      for (int k = 0; k < 4; ++k) sm.ered[w][k][lane] = dacc[k];
      __syncthreads();
      const int b2 = tid >> 2, kk = tid & 3;
      const double dv = sm.ered[0][kk][b2] + sm.ered[1][kk][b2] +
                        sm.ered[2][kk][b2] + sm.ered[3][kk][b2] + bd_r;
      st_l2_d(&dpw[(bG + b2)*256 + 4*r + kk], dv);
    }
    ++epoch; group_barrier(flags, rel, g, r, epoch);
    // ---------- (c) f64-exact scores -> np-faithful fp32 log_softmax ----------
    {
      const double dpl = ld1_l2_d(&dpw[myb*256 + tid]);
      for (int s = 0; s < 100; ++s) {
        const bool masked = (s < 64) ? (((m0 >> s) & 1ull) != 0ull)
                                     : (((m1 >> (s-64)) & 1ull) != 0ull);
        if (!masked) {   // block-uniform -> whole-wave skip
          // ep immutable after encoder: plain nontemporal load (fresh by
          // construction; nt avoids L2 pollution so weights stay resident).
          double p = tanh(__builtin_nontemporal_load(&myep[s*256]) + dpl) * vw_r;
          p = wave64_sum_d(p);
          if (lane == 0) sm.sred[s][w] = p;
        }
      }
      __syncthreads();
      if (tid < 100) {
        const bool masked = (tid < 64) ? (((m0 >> tid) & 1ull) != 0ull)
                                       : (((m1 >> (tid-64)) & 1ull) != 0ull);
        // single rounding of the exact score to fp32 (reference dtype)
        sm.scores[tid] = masked ? -__builtin_inff()
                                : (float)(sm.sred[tid][0] + sm.sred[tid][1] +
                                          sm.sred[tid][2] + sm.sred[tid][3] + vb0);
      }
      __syncthreads();
      if (w == 0) {   // m = max(scores), fp32
        const float v0 = sm.scores[lane];
        const float v1 = (lane < 36) ? sm.scores[64 + lane] : -__builtin_inff();
        float mv = fmaxf(v0, v1);
        #pragma unroll
        for (int mm = 1; mm < 64; mm <<= 1)
          mv = fmaxf(mv, __shfl_xor(mv, mm, 64));
        if (lane == 0) sm.red_m = mv;
      }
      __syncthreads();
      if (tid < 100)
        sm.evals[tid] = expf(__fsub_rn(sm.scores[tid], sm.red_m));
      __syncthreads();
      if (tid == 0) {
        // numpy pairwise_sum for n=100: 8 accumulators over 0..95,
        // combine ((r0+r1)+(r2+r3))+((r4+r5)+(r6+r7)), sequential tail 96..99
        float rr[8];
        #pragma unroll
        for (int j = 0; j < 8; ++j) rr[j] = sm.evals[j];
        for (int i = 8; i < 96; i += 8) {
          #pragma unroll
          for (int j = 0; j < 8; ++j) rr[j] = __fadd_rn(rr[j], sm.evals[i + j]);
        }
        float res = __fadd_rn(
            __fadd_rn(__fadd_rn(rr[0], rr[1]), __fadd_rn(rr[2], rr[3])),
            __fadd_rn(__fadd_rn(rr[4], rr[5]), __fadd_rn(rr[6], rr[7])));
        res = __fadd_rn(res, sm.evals[96]);
        res = __fadd_rn(res, sm.evals[97]);
        res = __fadd_rn(res, sm.evals[98]);
        res = __fadd_rn(res, sm.evals[99]);
        sm.red_L = logf(res);
      }
      __syncthreads();
      if (w == 0) {   // lp = fl(fl(s - m) - L); argmax(lp), first index on ties
        const float m = sm.red_m, L = sm.red_L;
        const float lp0 = __fsub_rn(__fsub_rn(sm.scores[lane], m), L);
        const float lp1 = (lane < 36)
            ? __fsub_rn(__fsub_rn(sm.scores[64 + lane], m), L)
            : -__builtin_inff();
        float bv; int bi;
        if (lp0 >= lp1) { bv = lp0; bi = lane; } else { bv = lp1; bi = 64 + lane; }
        #pragma unroll
        for (int mm = 1; mm < 64; mm <<= 1) {
          const float ov = __shfl_xor(bv, mm, 64);
          const int   oi = __shfl_xor(bi, mm, 64);
          if (ov > bv || (ov == bv && oi < bi)) { bv = ov; bi = oi; }
        }
        if (lane == 0) { sm.bc_sel = bi; sm.bc_lp = bv; }
      }
      __syncthreads();
      const int sel = __builtin_amdgcn_readfirstlane(sm.bc_sel);
      lp_acc = __fadd_rn(lp_acc, sm.bc_lp);   // np axis-0 sum: sequential fp32
      if (sel < 64) m0 |= (1ull << sel); else m1 |= (1ull << (sel - 64));
      if (tid == 0) out[myb*100 + t] = (float)sel;
      if (tid < 2) st_l2_f(&din[myb*2 + tid], xT[sel*1024 + myb*2 + tid]);
    }
    ++epoch; group_barrier(flags, rel, g, r, epoch);
  }

  // ---------------- outputs ----------------
  if (tid == 0) out[51200 + myb] = lp_acc;
  out[51712 + myb*256 + tid] = (float)ld1_l2_d(&hbuf[tid*512 + myb]);
}

extern "C" void kernel_launch(void* const* d_in, const int* in_sizes, int n_in,
                              void* d_out, int out_size, void* d_ws, size_t ws_size,
                              hipStream_t stream) {
  const float* x     = (const float*)d_in[0];
  const float* eWih  = (const float*)d_in[1];
  const float* eWhh  = (const float*)d_in[2];
  const float* ebih  = (const float*)d_in[3];
  const float* ebhh  = (const float*)d_in[4];
  const float* dWih  = (const float*)d_in[5];
  const float* dWhh  = (const float*)d_in[6];
  const float* dbih  = (const float*)d_in[7];
  const float* dbhh  = (const float*)d_in[8];
  const float* We    = (const float*)d_in[9];
  const float* be    = (const float*)d_in[10];
  const float* Wd    = (const float*)d_in[11];
  const float* bd    = (const float*)d_in[12];
  const float* vw    = (const float*)d_in[13];
  const float* vb    = (const float*)d_in[14];
  const float* start = (const float*)d_in[15];
  char* ws    = (char*)d_ws;
  float* outp = (float*)d_out;

  ptrnet_prep<<<dim3(512), dim3(256), 0, stream>>>(
      x, eWih, eWhh, ebih, ebhh, dWih, dWhh, dbih, dbhh, We, Wd, start, ws);

  ptrnet_main<<<dim3(512), dim3(256), 0, stream>>>(ws, be, bd, vw, vb, outp);
}

// Round 12
// 11477.855 us; speedup vs baseline: 2.4068x; 1.3807x over previous
//
#include <hip/hip_runtime.h>

// Pointer network: encoder LSTM -> enc_proj -> decoder LSTM + attention argmax.
// B=512, S=100, D=2, H=256.
//
// NUMERICS (FROZEN since R7, absmax 7.0 <= 7.2): f64 state trajectory (h/c/
// gates/ep/dp in f64; chain ORDER may vary -- error ~1e-13 << decision gaps)
// + EXACT np-faithful fp32 log_softmax selection (single f32 rounding of
// scores, pairwise-8 sum of exps, lp=fl(fl(s-m)-L), argmax(lp) first-index,
// lp_acc sequential fp32). Selection block below is byte-identical to R7-R11.
//
// R12: BARRIER-FREE restructure. Evidence chain R7-R11: any load that must see
// another block's store (atomic or sc0) forces an L2 miss on gfx950 -> the
// 64-fold h-broadcast + 400 global barriers pinned the old design at ~16 ms
// (46 ms with skew). The recurrence is independent PER BATCH ELEMENT given
// weights: one block per batch element (thread = hidden unit) makes h/c/din/
// dp/ep[b] block-private (LDS + same-CU global, plain cached ops). Zero
// inter-block communication, zero barriers, zero atomics. Weights re-stream
// from the XCD-local L2 each step (same 1.25 MB for all 64 blocks/XCD),
// stored as f32 packs -- EXACT, inputs are f32; cvt to f64 in-register.
//
// 512 blocks x 256 threads, plain launches, no co-residency requirement.

#define B_WHE  0ull                       // f32 [256 k][256 u][4 g] enc Whh^T
#define B_WHD  (B_WHE + 1048576ull)       // f32 dec
#define B_WET  (B_WHD + 1048576ull)       // f32 [256 k][256 u] We^T
#define B_WDT  (B_WET + 262144ull)        // f32 Wd^T
#define B_WXE  (B_WDT + 262144ull)        // f64 [256 u][16] Wih+bias pack
#define B_WXD  (B_WXE + 32768ull)
#define B_EP   (B_WXD + 32768ull)         // f64 [512 b][100 t][256 u] = 104.9MB

__device__ __forceinline__ double sigmoid_d(double x) {
  return 1.0 / (1.0 + exp(-x));
}

__device__ __forceinline__ double shfl_xor_d(double v, int m) {
  const long long l = __double_as_longlong(v);
  int lo = (int)(l & 0xffffffffll), hi = (int)(l >> 32);
  lo = __shfl_xor(lo, m, 64);
  hi = __shfl_xor(hi, m, 64);
  return __longlong_as_double(((long long)hi << 32) | (unsigned int)lo);
}

__device__ __forceinline__ double wave64_sum_d(double v) {
  #pragma unroll
  for (int m = 1; m < 64; m <<= 1) v += shfl_xor_d(v, m);
  return v;
}

struct SMem {
  double sred[100][4];
  float  scores[104];
  float  evals[104];
  float  red_m, red_L;
  float  bc_lp;
  int    bc_sel;
};

extern "C" __global__ void ptrnet_prep(
    const float* __restrict__ eWih, const float* __restrict__ eWhh,
    const float* __restrict__ ebih, const float* __restrict__ ebhh,
    const float* __restrict__ dWih, const float* __restrict__ dWhh,
    const float* __restrict__ dbih, const float* __restrict__ dbhh,
    const float* __restrict__ We,  const float* __restrict__ Wd,
    char* __restrict__ wsb)
{
  const int idx = blockIdx.x * blockDim.x + threadIdx.x;
  const int stride = gridDim.x * blockDim.x;
  float* WHE = (float*)(wsb + B_WHE);
  float* WHD = (float*)(wsb + B_WHD);
  float* WET = (float*)(wsb + B_WET);
  float* WDT = (float*)(wsb + B_WDT);
  double* WXE = (double*)(wsb + B_WXE);
  double* WXD = (double*)(wsb + B_WXD);

  // Whh^T packs: [k][u][gate] (f32 verbatim -- exact)
  for (int i = idx; i < 256*256*4; i += stride) {
    const int g = i & 3, u = (i >> 2) & 255, k = i >> 10;
    WHE[i] = eWhh[(g*256 + u)*256 + k];
    WHD[i] = dWhh[(g*256 + u)*256 + k];
  }
  // We^T / Wd^T: [k][u]
  for (int i = idx; i < 256*256; i += stride) {
    const int u = i & 255, k = i >> 8;
    WET[i] = We[u*256 + k];
    WDT[i] = Wd[u*256 + k];
  }
  // Wih + bias pack (f64): [u][16] = {i0,i1,f0,f1,g0,g1,o0,o1, bi,bf,bg,bo}
  for (int i = idx; i < 256*16; i += stride) {
    const int f = i & 15, u = i >> 4;
    double ve = 0.0, vd = 0.0;
    if (f < 8) {
      const int gg = f >> 1, d = f & 1;
      ve = (double)eWih[(gg*256+u)*2 + d];
      vd = (double)dWih[(gg*256+u)*2 + d];
    } else if (f < 12) {
      const int gg = f - 8;
      ve = (double)ebih[gg*256+u] + (double)ebhh[gg*256+u];
      vd = (double)dbih[gg*256+u] + (double)dbhh[gg*256+u];
    }
    WXE[i] = ve;
    WXD[i] = vd;
  }
}

extern "C" __global__ void __launch_bounds__(256, 2)
ptrnet_main(char* __restrict__ wsb,
            const float* __restrict__ x,
            const float* __restrict__ be,
            const float* __restrict__ bd,
            const float* __restrict__ Vw,
            const float* __restrict__ Vb,
            const float* __restrict__ start,
            float* __restrict__ out)
{
  __shared__ double hls[2][256];   // block-private h state, ping-pong
  __shared__ SMem sm;
  __shared__ float s_din[2];
  const int b   = blockIdx.x;      // one block per batch element
  const int tid = threadIdx.x;     // thread = hidden unit u
  const int lane = tid & 63;
  const int w = __builtin_amdgcn_readfirstlane(tid >> 6);

  const float* WHE = (const float*)(wsb + B_WHE);
  const float* WHD = (const float*)(wsb + B_WHD);
  const float* WET = (const float*)(wsb + B_WET);
  const float* WDT = (const float*)(wsb + B_WDT);
  const double* wxE = (const double*)(wsb + B_WXE) + tid*16;
  const double* wxD = (const double*)(wsb + B_WXD) + tid*16;
  double* ep = (double*)(wsb + B_EP) + (size_t)b*25600;   // block-private

  const double be_u = (double)be[tid];
  const double bd_u = (double)bd[tid];
  const double vw_r = (double)Vw[tid];
  const double vb0  = (double)Vb[0];

  double c_state = 0.0;
  int par = 0;
  hls[0][tid] = 0.0;
  if (tid < 2) s_din[tid] = start[tid];
  __syncthreads();

  // ============================ encoder ============================
  for (int t = 0; t < 100; ++t) {
    const double x0 = (double)x[(b*100 + t)*2 + 0];
    const double x1 = (double)x[(b*100 + t)*2 + 1];
    double a0 = 0.0, a1 = 0.0, a2 = 0.0, a3 = 0.0, ae = 0.0;
    const double* hrow = hls[par];
    #pragma unroll 4
    for (int k = 0; k < 256; ++k) {
      const double hk = hrow[k];                       // LDS broadcast
      const float4 wf = *(const float4*)(WHE + k*1024 + tid*4);
      const float  we = WET[k*256 + tid];
      a0 = fma((double)wf.x, hk, a0);
      a1 = fma((double)wf.y, hk, a1);
      a2 = fma((double)wf.z, hk, a2);
      a3 = fma((double)wf.w, hk, a3);
      ae = fma((double)we,  hk, ae);
    }
    const double gi = a0 + fma(wxE[0], x0, fma(wxE[1], x1, wxE[8]));
    const double gf = a1 + fma(wxE[2], x0, fma(wxE[3], x1, wxE[9]));
    const double gg = a2 + fma(wxE[4], x0, fma(wxE[5], x1, wxE[10]));
    const double go = a3 + fma(wxE[6], x0, fma(wxE[7], x1, wxE[11]));
    const double cn = sigmoid_d(gf)*c_state + sigmoid_d(gi)*tanh(gg);
    const double hn = sigmoid_d(go)*tanh(cn);
    c_state = cn;
    if (t > 0) ep[(t-1)*256 + tid] = ae + be_u;   // ep[t-1] = We*h^(t)+be
    hls[par ^ 1][tid] = hn;
    __syncthreads();
    par ^= 1;
  }
  // ep[99] from h^(100)
  {
    double ae = 0.0;
    const double* hrow = hls[par];
    #pragma unroll 4
    for (int k = 0; k < 256; ++k)
      ae = fma((double)WET[k*256 + tid], hrow[k], ae);
    ep[99*256 + tid] = ae + be_u;
  }

  // ===================== decoder =====================
  unsigned long long m0 = 0ull, m1 = 0ull;
  float lp_acc = 0.0f;

  for (int t = 0; t < 100; ++t) {
    // ---------- LSTM cell ----------
    {
      const double x0 = (double)s_din[0];
      const double x1 = (double)s_din[1];
      double a0 = 0.0, a1 = 0.0, a2 = 0.0, a3 = 0.0;
      const double* hrow = hls[par];
      #pragma unroll 4
      for (int k = 0; k < 256; ++k) {
        const double hk = hrow[k];
        const float4 wf = *(const float4*)(WHD + k*1024 + tid*4);
        a0 = fma((double)wf.x, hk, a0);
        a1 = fma((double)wf.y, hk, a1);
        a2 = fma((double)wf.z, hk, a2);
        a3 = fma((double)wf.w, hk, a3);
      }
      const double gi = a0 + fma(wxD[0], x0, fma(wxD[1], x1, wxD[8]));
      const double gf = a1 + fma(wxD[2], x0, fma(wxD[3], x1, wxD[9]));
      const double gg = a2 + fma(wxD[4], x0, fma(wxD[5], x1, wxD[10]));
      const double go = a3 + fma(wxD[6], x0, fma(wxD[7], x1, wxD[11]));
      const double cn = sigmoid_d(gf)*c_state + sigmoid_d(gi)*tanh(gg);
      const double hn = sigmoid_d(go)*tanh(cn);
      c_state = cn;
      hls[par ^ 1][tid] = hn;
      __syncthreads();
      par ^= 1;
    }
    // ---------- dec_proj row (block-local) ----------
    double dpl;
    {
      double ad = 0.0;
      const double* hrow = hls[par];
      #pragma unroll 4
      for (int k = 0; k < 256; ++k)
        ad = fma((double)WDT[k*256 + tid], hrow[k], ad);
      dpl = ad + bd_u;
    }
    // ---------- f64-exact scores -> np-faithful fp32 log_softmax ----------
    {
      for (int s = 0; s < 100; ++s) {
        const bool masked = (s < 64) ? (((m0 >> s) & 1ull) != 0ull)
                                     : (((m1 >> (s-64)) & 1ull) != 0ull);
        if (!masked) {   // block-uniform -> whole-wave skip
          double p = tanh(ep[s*256 + tid] + dpl) * vw_r;
          p = wave64_sum_d(p);
          if (lane == 0) sm.sred[s][w] = p;
        }
      }
      __syncthreads();
      if (tid < 100) {
        const bool masked = (tid < 64) ? (((m0 >> tid) & 1ull) != 0ull)
                                       : (((m1 >> (tid-64)) & 1ull) != 0ull);
        // single rounding of the exact score to fp32 (reference dtype)
        sm.scores[tid] = masked ? -__builtin_inff()
                                : (float)(sm.sred[tid][0] + sm.sred[tid][1] +
                                          sm.sred[tid][2] + sm.sred[tid][3] + vb0);
      }
      __syncthreads();
      if (w == 0) {   // m = max(scores), fp32
        const float v0 = sm.scores[lane];
        const float v1 = (lane < 36) ? sm.scores[64 + lane] : -__builtin_inff();
        float mv = fmaxf(v0, v1);
        #pragma unroll
        for (int mm = 1; mm < 64; mm <<= 1)
          mv = fmaxf(mv, __shfl_xor(mv, mm, 64));
        if (lane == 0) sm.red_m = mv;
      }
      __syncthreads();
      if (tid < 100)
        sm.evals[tid] = expf(__fsub_rn(sm.scores[tid], sm.red_m));
      __syncthreads();
      if (tid == 0) {
        // numpy pairwise_sum for n=100: 8 accumulators over 0..95,
        // combine ((r0+r1)+(r2+r3))+((r4+r5)+(r6+r7)), sequential tail 96..99
        float rr[8];
        #pragma unroll
        for (int j = 0; j < 8; ++j) rr[j] = sm.evals[j];
        for (int i = 8; i < 96; i += 8) {
          #pragma unroll
          for (int j = 0; j < 8; ++j) rr[j] = __fadd_rn(rr[j], sm.evals[i + j]);
        }
        float res = __fadd_rn(
            __fadd_rn(__fadd_rn(rr[0], rr[1]), __fadd_rn(rr[2], rr[3])),
            __fadd_rn(__fadd_rn(rr[4], rr[5]), __fadd_rn(rr[6], rr[7])));
        res = __fadd_rn(res, sm.evals[96]);
        res = __fadd_rn(res, sm.evals[97]);
        res = __fadd_rn(res, sm.evals[98]);
        res = __fadd_rn(res, sm.evals[99]);
        sm.red_L = logf(res);
      }
      __syncthreads();
      if (w == 0) {   // lp = fl(fl(s - m) - L); argmax(lp), first index on ties
        const float m = sm.red_m, L = sm.red_L;
        const float lp0 = __fsub_rn(__fsub_rn(sm.scores[lane], m), L);
        const float lp1 = (lane < 36)
            ? __fsub_rn(__fsub_rn(sm.scores[64 + lane], m), L)
            : -__builtin_inff();
        float bv; int bi;
        if (lp0 >= lp1) { bv = lp0; bi = lane; } else { bv = lp1; bi = 64 + lane; }
        #pragma unroll
        for (int mm = 1; mm < 64; mm <<= 1) {
          const float ov = __shfl_xor(bv, mm, 64);
          const int   oi = __shfl_xor(bi, mm, 64);
          if (ov > bv || (ov == bv && oi < bi)) { bv = ov; bi = oi; }
        }
        if (lane == 0) { sm.bc_sel = bi; sm.bc_lp = bv; }
      }
      __syncthreads();
      const int sel = __builtin_amdgcn_readfirstlane(sm.bc_sel);
      lp_acc = __fadd_rn(lp_acc, sm.bc_lp);   // np axis-0 sum: sequential fp32
      if (sel < 64) m0 |= (1ull << sel); else m1 |= (1ull << (sel - 64));
      if (tid == 0) out[b*100 + t] = (float)sel;
      if (tid < 2) s_din[tid] = x[(b*100 + sel)*2 + tid];
      __syncthreads();
    }
  }

  // ---------------- outputs ----------------
  if (tid == 0) out[51200 + b] = lp_acc;
  out[51712 + b*256 + tid] = (float)hls[par][tid];
}

extern "C" void kernel_launch(void* const* d_in, const int* in_sizes, int n_in,
                              void* d_out, int out_size, void* d_ws, size_t ws_size,
                              hipStream_t stream) {
  const float* x     = (const float*)d_in[0];
  const float* eWih  = (const float*)d_in[1];
  const float* eWhh  = (const float*)d_in[2];
  const float* ebih  = (const float*)d_in[3];
  const float* ebhh  = (const float*)d_in[4];
  const float* dWih  = (const float*)d_in[5];
  const float* dWhh  = (const float*)d_in[6];
  const float* dbih  = (const float*)d_in[7];
  const float* dbhh  = (const float*)d_in[8];
  const float* We    = (const float*)d_in[9];
  const float* be    = (const float*)d_in[10];
  const float* Wd    = (const float*)d_in[11];
  const float* bd    = (const float*)d_in[12];
  const float* vw    = (const float*)d_in[13];
  const float* vb    = (const float*)d_in[14];
  const float* start = (const float*)d_in[15];
  char* ws    = (char*)d_ws;
  float* outp = (float*)d_out;

  ptrnet_prep<<<dim3(512), dim3(256), 0, stream>>>(
      eWih, eWhh, ebih, ebhh, dWih, dWhh, dbih, dbhh, We, Wd, ws);

  ptrnet_main<<<dim3(512), dim3(256), 0, stream>>>(ws, x, be, bd, vw, vb,
                                                   start, outp);
}